// Round 4
// baseline (1162.125 us; speedup 1.0000x reference)
//
#include <hip/hip_runtime.h>
#include <hip/hip_bf16.h>

#define NN 50000
#define EE 100000
#define BB 2000
#define DIM 64
#define NF 14
#define EF 4
#define HID 128
#define EPAD 100096  // 391 * 256

typedef __attribute__((ext_vector_type(8))) _Float16 half8;   // 4 VGPRs
typedef __attribute__((ext_vector_type(4))) _Float16 half4;
typedef __attribute__((ext_vector_type(4))) float floatx4;    // MFMA C/D

// ---------------- weight transposes for set2set ----------------
__global__ void transpose_kernel(const float* __restrict__ lih, const float* __restrict__ lhh,
                                 const float* __restrict__ l1,
                                 float* __restrict__ lihT, float* __restrict__ lhhT,
                                 float* __restrict__ l1T) {
    int t = blockIdx.x * 256 + threadIdx.x;
    if (t < 256 * 128) { int j = t / 128, k = t % 128; lihT[k * 256 + j] = lih[t]; }
    if (t < 256 * 64) { int j = t / 64, k = t % 64; lhhT[k * 256 + j] = lhh[t]; }
    if (t < 64 * 128) { int d = t / 128, k = t % 128; l1T[k * 64 + d] = l1[t]; }
}

// ---------------- fused fp16 weight prep for node_fused ----------------
__global__ void prep_gru_kernel(const float* __restrict__ root, const float* __restrict__ b2,
                                const float* __restrict__ wih, const float* __restrict__ whh,
                                const float* __restrict__ bih, const float* __restrict__ bhh,
                                _Float16* __restrict__ W1h, _Float16* __restrict__ W2h,
                                float* __restrict__ fbias) {
    int t = blockIdx.x * 256 + threadIdx.x;
    if (t < 64 * 128) {
        int n = t >> 7, k = t & 127;
        W1h[t] = (_Float16)(k < 64 ? root[k * 64 + n] : b2[(size_t)(k - 64) * 64 + n]);
    }
    if (t < 256 * 128) {
        int n2 = t >> 7, k = t & 127;
        int g = n2 >> 6, j = n2 & 63;
        float v;
        if (g == 0)      v = (k < 64) ? wih[j * 64 + k]         : whh[j * 64 + (k - 64)];
        else if (g == 1) v = (k < 64) ? wih[(64 + j) * 64 + k]  : whh[(64 + j) * 64 + (k - 64)];
        else if (g == 2) v = (k < 64) ? wih[(128 + j) * 64 + k] : 0.f;
        else             v = (k < 64) ? 0.f                     : whh[(128 + j) * 64 + (k - 64)];
        W2h[t] = (_Float16)v;
    }
    if (t < 256) {
        int g = t >> 6, j = t & 63;
        float v = (g == 0) ? bih[j] + bhh[j]
                : (g == 1) ? bih[64 + j] + bhh[64 + j]
                : (g == 2) ? bih[128 + j] : bhh[128 + j];
        fbias[t] = v;
    }
}

// ---------------- out0 = relu(x @ lin0_w.T + b) ----------------
__global__ void lin0_kernel(const float* __restrict__ x, const float* __restrict__ w,
                            const float* __restrict__ b, float* __restrict__ hv) {
    int t = blockIdx.x * 256 + threadIdx.x;
    if (t >= NN * 64) return;
    int n = t >> 6, d = t & 63;
    float acc = b[d];
    #pragma unroll
    for (int f = 0; f < NF; f++) acc += x[n * NF + f] * w[d * NF + f];
    hv[t] = fmaxf(acc, 0.f);
}

// ---------------- in-degree ----------------
__global__ void deg_kernel(const int* __restrict__ ei, float* __restrict__ deg) {
    int e = blockIdx.x * 256 + threadIdx.x;
    if (e < EE) atomicAdd(&deg[ei[EE + e]], 1.0f);
}

// ---------------- he16 = fp16(relu(edge_attr @ w1.T + b1)), zero-padded to EPAD ----------------
__global__ void he16_kernel(const float* __restrict__ ea, const float* __restrict__ w1,
                            const float* __restrict__ b1, _Float16* __restrict__ he) {
    int t = blockIdx.x * 256 + threadIdx.x;
    if (t >= EPAD * 128) return;
    int el = t >> 7, h = t & 127;
    float acc = 0.f;
    if (el < EE) {
        const float4 a = *(const float4*)(ea + (size_t)el * 4);
        const float4 w = *(const float4*)(w1 + h * 4);
        acc = fmaxf(b1[h] + a.x * w.x + a.y * w.y + a.z * w.z + a.w * w.w, 0.f);
    }
    he[t] = (_Float16)acc;
}

// ---------------- W2rT[o][i*128+h] = fp16(mlp_w2[(i*64+o)*128 + h]) ----------------
__global__ void w2rt_kernel(const float* __restrict__ w2, _Float16* __restrict__ W2rT) {
    int t = blockIdx.x * 256 + threadIdx.x;
    if (t >= 64 * 8192) return;
    int o = t >> 13, k = t & 8191, i = k >> 7, h = k & 127;
    W2rT[(size_t)o * 8192 + k] = (_Float16)w2[(size_t)(i * 64 + o) * 128 + h];
}

// ---------------- msg GEMM: msg = G @ W2rT^T, G generated in-register ----------------
// Round-9: verified 134us structure (256-edge tile, waves split on M, 64 MFMA/wave/i)
// but B is loaded DIRECTLY from global into registers (half-i double-buffered) instead
// of LDS-staged:
//   - the 16KB B i-slice is identical across all 8 resident waves -> L1-resident
//     (per-CU demand ~52 B/cyc over the 2483-cyc MFMA window);
//   - removes per-i: 16 ds_read_b128 + 4 ds_write_b128 + __syncthreads (the measured
//     ~1730 cyc LDS path + barrier drain that capped the base at 50% of its MFMA floor);
//   - K-loop is barrier-free; only one prologue barrier for sXs.
__global__ __launch_bounds__(256, 2) void msg_gemm_kernel(
    const float* __restrict__ hv, const _Float16* __restrict__ he16,
    const _Float16* __restrict__ W2rT, const int* __restrict__ ei,
    float* __restrict__ agg, float* __restrict__ xsum) {
    __shared__ _Float16 sXs[256 * 68];        // [edge][i], padded stride 68
    __shared__ int sDst[256];
    const int t = threadIdx.x;
    const int eb = blockIdx.x * 256;
    const int lane = t & 63;
    const int w = t >> 6;
    const int col = lane & 15;
    const int quad = lane >> 4;

    if (t < 256) {
        int e = eb + t;
        sDst[t] = (e < EE) ? ei[EE + e] : 0;
    }
    #pragma unroll 4
    for (int rep = 0; rep < 16; rep++) {
        int idx = rep * 256 + t;
        int el = idx >> 4, d4 = idx & 15;
        int e = eb + el;
        float4 v = {0.f, 0.f, 0.f, 0.f};
        if (e < EE) {
            int src = ei[e];
            v = *(const float4*)(hv + (size_t)src * 64 + d4 * 4);
        }
        half4 h4 = {(_Float16)v.x, (_Float16)v.y, (_Float16)v.z, (_Float16)v.w};
        *(half4*)&sXs[el * 68 + d4 * 4] = h4;
    }

    // he fragments: wave w owns edges [w*64, w*64+64), register-resident across all i
    half8 heReg[4][4];
    #pragma unroll
    for (int mt = 0; mt < 4; mt++) {
        int row = eb + w * 64 + mt * 16 + col;
        #pragma unroll
        for (int p = 0; p < 4; p++)
            heReg[mt][p] = *(const half8*)(he16 + (size_t)row * 128 + p * 32 + quad * 8);
    }

    floatx4 Cacc[4][4];
    #pragma unroll
    for (int mt = 0; mt < 4; mt++)
        #pragma unroll
        for (int nt = 0; nt < 4; nt++)
            Cacc[mt][nt] = (floatx4){0.f, 0.f, 0.f, 0.f};

    __syncthreads();   // sXs ready; no further barriers

    // per-lane B base: fragment (nt, ks) of slice i lives at
    //   pB + nt*16*8192 + i*128 + ks*32   (same addresses the old sB staging used)
    const _Float16* pB = W2rT + (size_t)col * 8192 + quad * 8;

    half8 B0[4][2], B1[4][2];   // [nt][ks-local], half-i double buffer
    auto LOADK = [&](half8 (&dst)[4][2], int i, int ksb) {
        #pragma unroll
        for (int nt = 0; nt < 4; nt++)
            #pragma unroll
            for (int kl = 0; kl < 2; kl++)
                dst[nt][kl] = *(const half8*)(pB + (size_t)nt * (16 * 8192)
                                              + (size_t)i * 128 + (ksb + kl) * 32);
    };
    auto HALF = [&](half8 (&b)[4][2], const _Float16 (&xsx)[4], int ksb) {
        #pragma unroll
        for (int kl = 0; kl < 2; kl++) {
            #pragma unroll
            for (int mt = 0; mt < 4; mt++) {
                half8 afr = heReg[mt][ksb + kl] * xsx[mt];
                #pragma unroll
                for (int nt = 0; nt < 4; nt++)
                    Cacc[mt][nt] = __builtin_amdgcn_mfma_f32_16x16x32_f16(afr, b[nt][kl], Cacc[mt][nt], 0, 0, 0);
            }
        }
    };

    LOADK(B0, 0, 0);
    #pragma unroll 1
    for (int i = 0; i < 64; i++) {
        LOADK(B1, i, 2);                    // ks 2,3 of slice i
        _Float16 xsx[4];
        #pragma unroll
        for (int mt = 0; mt < 4; mt++)
            xsx[mt] = sXs[(w * 64 + mt * 16 + col) * 68 + i];
        HALF(B0, xsx, 0);                   // 32 MFMA on ks 0,1
        if (i < 63) LOADK(B0, i + 1, 0);    // ks 0,1 of slice i+1
        HALF(B1, xsx, 2);                   // 32 MFMA on ks 2,3
    }

    // epilogue: scatter msg into agg (atomic), then xsum
    #pragma unroll
    for (int mt = 0; mt < 4; mt++) {
        #pragma unroll
        for (int r = 0; r < 4; r++) {
            int el = w * 64 + mt * 16 + quad * 4 + r;
            if (eb + el < EE) {
                float* ap = agg + (size_t)sDst[el] * 64 + col;
                #pragma unroll
                for (int nt = 0; nt < 4; nt++)
                    atomicAdd(ap + nt * 16, Cacc[mt][nt][r]);
            }
        }
    }
    #pragma unroll 4
    for (int rep = 0; rep < 64; rep++) {
        int idx = rep * 256 + t;
        int el = idx >> 6, d = idx & 63;
        if (eb + el < EE)
            atomicAdd(&xsum[(size_t)sDst[el] * 64 + d], (float)sXs[el * 68 + d]);
    }
}

// ---------------- fused node update: NNConv epilogue + GRU (MFMA) ----------------
// Also re-zeros agg/xsum after consuming them (saves per-iteration memset dispatches).
__global__ __launch_bounds__(256, 2) void node_fused_kernel(
    const float* __restrict__ hv_in, float* __restrict__ agg,
    float* __restrict__ xsum, const float* __restrict__ deg,
    const _Float16* __restrict__ W1h, const _Float16* __restrict__ W2h,
    const float* __restrict__ fbias, const float* __restrict__ cb,
    float* __restrict__ hv_out) {
    __shared__ _Float16 sA1[64 * 136];  // [node][k]: k<64 hv, k>=64 xsum/deg
    __shared__ _Float16 sA2[64 * 136];  // [node][k]: k<64 m, k>=64 hv
    __shared__ float sH[64 * 68];       // h_old fp32, reused for h_new
    __shared__ float sAgg[64 * 68];     // agg/deg fp32
    const int t = threadIdx.x;
    const int nb = blockIdx.x * 64;
    const int n = t >> 2, part = t & 3;
    {
        int gn = nb + n;
        bool valid = gn < NN;
        float inv = 1.f;
        if (valid) inv = 1.f / fmaxf(deg[gn], 1.f);
        #pragma unroll
        for (int c4 = 0; c4 < 4; c4++) {
            int d0 = part * 16 + c4 * 4;
            float4 hvv = {0.f, 0.f, 0.f, 0.f}, agv = {0.f, 0.f, 0.f, 0.f}, xsv = {0.f, 0.f, 0.f, 0.f};
            if (valid) {
                hvv = *(const float4*)(hv_in + (size_t)gn * 64 + d0);
                agv = *(const float4*)(agg + (size_t)gn * 64 + d0);
                xsv = *(const float4*)(xsum + (size_t)gn * 64 + d0);
            }
            agv.x *= inv; agv.y *= inv; agv.z *= inv; agv.w *= inv;
            xsv.x *= inv; xsv.y *= inv; xsv.z *= inv; xsv.w *= inv;
            half4 hvh = {(_Float16)hvv.x, (_Float16)hvv.y, (_Float16)hvv.z, (_Float16)hvv.w};
            half4 xsh = {(_Float16)xsv.x, (_Float16)xsv.y, (_Float16)xsv.z, (_Float16)xsv.w};
            *(half4*)&sA1[n * 136 + d0] = hvh;
            *(half4*)&sA1[n * 136 + 64 + d0] = xsh;
            *(half4*)&sA2[n * 136 + 64 + d0] = hvh;
            *(float4*)&sH[n * 68 + d0] = hvv;
            *(float4*)&sAgg[n * 68 + d0] = agv;
        }
        // re-zero agg/xsum for the next msg_gemm launch
        if (valid) {
            float4 z = {0.f, 0.f, 0.f, 0.f};
            #pragma unroll
            for (int c4 = 0; c4 < 4; c4++) {
                int d0 = part * 16 + c4 * 4;
                *(float4*)(agg + (size_t)gn * 64 + d0) = z;
                *(float4*)(xsum + (size_t)gn * 64 + d0) = z;
            }
        }
    }
    __syncthreads();

    const int lane = t & 63, w = t >> 6;
    const int col = lane & 15, quad = lane >> 4;

    // ---- stage 1 ----
    floatx4 C1[4];
    #pragma unroll
    for (int nt = 0; nt < 4; nt++) {
        float b = cb[nt * 16 + col];
        C1[nt] = (floatx4){b, b, b, b};
    }
    #pragma unroll
    for (int ks = 0; ks < 4; ks++) {
        half8 a = *(const half8*)&sA1[(w * 16 + col) * 136 + ks * 32 + quad * 8];
        #pragma unroll
        for (int nt = 0; nt < 4; nt++) {
            half8 bfr = *(const half8*)(W1h + (size_t)(nt * 16 + col) * 128 + ks * 32 + quad * 8);
            C1[nt] = __builtin_amdgcn_mfma_f32_16x16x32_f16(a, bfr, C1[nt], 0, 0, 0);
        }
    }
    #pragma unroll
    for (int nt = 0; nt < 4; nt++) {
        #pragma unroll
        for (int r = 0; r < 4; r++) {
            int node = w * 16 + quad * 4 + r;
            int j = nt * 16 + col;
            float m = fmaxf(C1[nt][r] + sAgg[node * 68 + j], 0.f);
            sA2[node * 136 + j] = (_Float16)m;
        }
    }
    __syncthreads();

    // ---- stage 2 ----
    floatx4 C2[16];
    #pragma unroll
    for (int nt2 = 0; nt2 < 16; nt2++) {
        float b = fbias[nt2 * 16 + col];
        C2[nt2] = (floatx4){b, b, b, b};
    }
    #pragma unroll
    for (int ks = 0; ks < 4; ks++) {
        half8 a = *(const half8*)&sA2[(w * 16 + col) * 136 + ks * 32 + quad * 8];
        #pragma unroll
        for (int nt2 = 0; nt2 < 16; nt2++) {
            half8 bfr = *(const half8*)(W2h + (size_t)(nt2 * 16 + col) * 128 + ks * 32 + quad * 8);
            C2[nt2] = __builtin_amdgcn_mfma_f32_16x16x32_f16(a, bfr, C2[nt2], 0, 0, 0);
        }
    }
    float hnew[4][4];
    #pragma unroll
    for (int r = 0; r < 4; r++) {
        int node = w * 16 + quad * 4 + r;
        #pragma unroll
        for (int jt = 0; jt < 4; jt++) {
            int j = jt * 16 + col;
            float rr = 1.f / (1.f + expf(-C2[jt][r]));
            float zz = 1.f / (1.f + expf(-C2[4 + jt][r]));
            float ng = tanhf(C2[8 + jt][r] + rr * C2[12 + jt][r]);
            float hold = sH[node * 68 + j];
            hnew[r][jt] = (1.f - zz) * ng + zz * hold;
        }
    }
    __syncthreads();
    #pragma unroll
    for (int r = 0; r < 4; r++) {
        int node = w * 16 + quad * 4 + r;
        #pragma unroll
        for (int jt = 0; jt < 4; jt++)
            sH[node * 68 + jt * 16 + col] = hnew[r][jt];
    }
    __syncthreads();
    {
        int gn = nb + n;
        if (gn < NN) {
            #pragma unroll
            for (int c4 = 0; c4 < 4; c4++) {
                int d0 = part * 16 + c4 * 4;
                *(float4*)(hv_out + (size_t)gn * 64 + d0) = *(const float4*)&sH[n * 68 + d0];
            }
        }
    }
}

// ---------------- fused Set2Set (3 steps) + readout, one block per graph ----------------
__global__ __launch_bounds__(256) void set2set_kernel(
    const float* __restrict__ hv,
    const float* __restrict__ lihT, const float* __restrict__ lhhT,
    const float* __restrict__ l_bih, const float* __restrict__ l_bhh,
    const float* __restrict__ lin1T, const float* __restrict__ lin1_b,
    const float* __restrict__ lin2_w, const float* __restrict__ lin2_b,
    float* __restrict__ out) {
    __shared__ float outS[25 * 65];
    __shared__ float qs[128], qh[64], qc[64], gat[256], ew[32], aw[32], red[64];
    int g = blockIdx.x;
    int t = threadIdx.x;
    for (int p = t; p < 25 * 64; p += 256) {
        int j = p >> 6, i = p & 63;
        outS[j * 65 + i] = hv[(size_t)(g * 25 + j) * 64 + i];
    }
    if (t < 128) qs[t] = 0.f;
    if (t < 64) { qh[t] = 0.f; qc[t] = 0.f; }
    __syncthreads();
    for (int it = 0; it < 3; it++) {
        float acc = l_bih[t] + l_bhh[t];
        for (int k = 0; k < 128; k++) acc += qs[k] * lihT[k * 256 + t];
        for (int k = 0; k < 64; k++) acc += qh[k] * lhhT[k * 256 + t];
        gat[t] = acc;
        __syncthreads();
        if (t < 64) {
            float ig = 1.f / (1.f + expf(-gat[t]));
            float fg = 1.f / (1.f + expf(-gat[64 + t]));
            float gg = tanhf(gat[128 + t]);
            float og = 1.f / (1.f + expf(-gat[192 + t]));
            float c = fg * qc[t] + ig * gg;
            qc[t] = c;
            qh[t] = og * tanhf(c);
        }
        __syncthreads();
        if (t < 25) {
            float e = 0.f;
            for (int i = 0; i < 64; i++) e += outS[t * 65 + i] * qh[i];
            ew[t] = e;
        }
        __syncthreads();
        if (t == 0) {
            float mx = ew[0];
            for (int j = 1; j < 25; j++) mx = fmaxf(mx, ew[j]);
            float s = 0.f;
            for (int j = 0; j < 25; j++) { float a = expf(ew[j] - mx); aw[j] = a; s += a; }
            float inv = 1.f / s;
            for (int j = 0; j < 25; j++) aw[j] *= inv;
        }
        __syncthreads();
        if (t < 64) {
            float r = 0.f;
            for (int j = 0; j < 25; j++) r += aw[j] * outS[j * 65 + t];
            qs[t] = qh[t];
            qs[64 + t] = r;
        }
        __syncthreads();
    }
    if (t < 64) {
        float y1 = lin1_b[t];
        for (int k = 0; k < 128; k++) y1 += qs[k] * lin1T[k * 64 + t];
        y1 = fmaxf(y1, 0.f);
        red[t] = y1 * lin2_w[t];
    }
    __syncthreads();
    if (t == 0) {
        float y = lin2_b[0];
        for (int i = 0; i < 64; i++) y += red[i];
        out[g] = y;
    }
}

extern "C" void kernel_launch(void* const* d_in, const int* in_sizes, int n_in,
                              void* d_out, int out_size, void* d_ws, size_t ws_size,
                              hipStream_t stream) {
    const float* x        = (const float*)d_in[0];
    const float* ea       = (const float*)d_in[1];
    const int*   ei       = (const int*)  d_in[2];
    const float* lin0_w   = (const float*)d_in[4];
    const float* lin0_b   = (const float*)d_in[5];
    const float* mlp_w1   = (const float*)d_in[6];
    const float* mlp_b1   = (const float*)d_in[7];
    const float* mlp_w2   = (const float*)d_in[8];
    const float* mlp_b2   = (const float*)d_in[9];
    const float* root     = (const float*)d_in[10];
    const float* conv_b   = (const float*)d_in[11];
    const float* gru_wih  = (const float*)d_in[12];
    const float* gru_whh  = (const float*)d_in[13];
    const float* gru_bih  = (const float*)d_in[14];
    const float* gru_bhh  = (const float*)d_in[15];
    const float* lstm_wih = (const float*)d_in[16];
    const float* lstm_whh = (const float*)d_in[17];
    const float* lstm_bih = (const float*)d_in[18];
    const float* lstm_bhh = (const float*)d_in[19];
    const float* lin1_w   = (const float*)d_in[20];
    const float* lin1_b   = (const float*)d_in[21];
    const float* lin2_w   = (const float*)d_in[22];
    const float* lin2_b   = (const float*)d_in[23];
    float* out = (float*)d_out;

    // ---- workspace carve ----
    char* base = (char*)d_ws;
    size_t off = 0;
    auto carve = [&](size_t bytes) -> void* {
        void* r = base + off;
        off = (off + bytes + 255) & ~(size_t)255;
        return r;
    };
    float* hv   = (float*)carve((size_t)NN * 64 * 4);
    float* agg  = (float*)carve((size_t)NN * 64 * 4);   // agg+xsum adjacent: one memset
    float* xsum = (float*)carve((size_t)NN * 64 * 4);
    float* deg  = (float*)carve((size_t)NN * 4);
    float* lihT = (float*)carve(128 * 256 * 4);
    float* lhhT = (float*)carve(64 * 256 * 4);
    float* l1T  = (float*)carve(128 * 64 * 4);
    float* fbias = (float*)carve(256 * 4);
    _Float16* he16 = (_Float16*)carve((size_t)EPAD * 128 * 2);
    _Float16* W2rT = (_Float16*)carve((size_t)64 * 8192 * 2);
    _Float16* W1h  = (_Float16*)carve((size_t)64 * 128 * 2);
    _Float16* W2h  = (_Float16*)carve((size_t)256 * 128 * 2);

    // ---- preamble ----
    hipMemsetAsync(deg, 0, (size_t)NN * 4, stream);
    hipMemsetAsync(agg, 0, (size_t)NN * 64 * 4 * 2, stream);  // agg + xsum (adjacent)
    transpose_kernel<<<128, 256, 0, stream>>>(lstm_wih, lstm_whh, lin1_w, lihT, lhhT, l1T);
    prep_gru_kernel<<<128, 256, 0, stream>>>(root, mlp_b2, gru_wih, gru_whh, gru_bih, gru_bhh,
                                             W1h, W2h, fbias);
    lin0_kernel<<<(NN * 64 + 255) / 256, 256, 0, stream>>>(x, lin0_w, lin0_b, hv);
    deg_kernel<<<(EE + 255) / 256, 256, 0, stream>>>(ei, deg);
    he16_kernel<<<(EPAD * 128 + 255) / 256, 256, 0, stream>>>(ea, mlp_w1, mlp_b1, he16);
    w2rt_kernel<<<(64 * 8192 + 255) / 256, 256, 0, stream>>>(mlp_w2, W2rT);

    // ---- 3 message-passing + GRU iterations (node_fused re-zeros agg/xsum) ----
    for (int it = 0; it < 3; it++) {
        msg_gemm_kernel<<<EPAD / 256, 256, 0, stream>>>(hv, he16, W2rT, ei, agg, xsum);
        node_fused_kernel<<<(NN + 63) / 64, 256, 0, stream>>>(hv, agg, xsum, deg,
                                                              W1h, W2h, fbias, conv_b, hv);
    }

    // ---- Set2Set + readout ----
    set2set_kernel<<<BB, 256, 0, stream>>>(hv, lihT, lhhT, lstm_bih, lstm_bhh,
                                           l1T, lin1_b, lin2_w, lin2_b, out);
}

// Round 5
// 814.566 us; speedup vs baseline: 1.4267x; 1.4267x over previous
//
#include <hip/hip_runtime.h>
#include <hip/hip_bf16.h>

#define NN 50000
#define EE 100000
#define BB 2000
#define DIM 64
#define NF 14
#define EF 4
#define HID 128
#define EPAD 100096  // 391 * 256

typedef __attribute__((ext_vector_type(8))) _Float16 half8;   // 4 VGPRs
typedef __attribute__((ext_vector_type(4))) _Float16 half4;
typedef __attribute__((ext_vector_type(4))) float floatx4;    // MFMA C/D

// ---------------- weight transposes for set2set ----------------
__global__ void transpose_kernel(const float* __restrict__ lih, const float* __restrict__ lhh,
                                 const float* __restrict__ l1,
                                 float* __restrict__ lihT, float* __restrict__ lhhT,
                                 float* __restrict__ l1T) {
    int t = blockIdx.x * 256 + threadIdx.x;
    if (t < 256 * 128) { int j = t / 128, k = t % 128; lihT[k * 256 + j] = lih[t]; }
    if (t < 256 * 64) { int j = t / 64, k = t % 64; lhhT[k * 256 + j] = lhh[t]; }
    if (t < 64 * 128) { int d = t / 128, k = t % 128; l1T[k * 64 + d] = l1[t]; }
}

// ---------------- fused fp16 weight prep for node_fused ----------------
__global__ void prep_gru_kernel(const float* __restrict__ root, const float* __restrict__ b2,
                                const float* __restrict__ wih, const float* __restrict__ whh,
                                const float* __restrict__ bih, const float* __restrict__ bhh,
                                _Float16* __restrict__ W1h, _Float16* __restrict__ W2h,
                                float* __restrict__ fbias) {
    int t = blockIdx.x * 256 + threadIdx.x;
    if (t < 64 * 128) {
        int n = t >> 7, k = t & 127;
        W1h[t] = (_Float16)(k < 64 ? root[k * 64 + n] : b2[(size_t)(k - 64) * 64 + n]);
    }
    if (t < 256 * 128) {
        int n2 = t >> 7, k = t & 127;
        int g = n2 >> 6, j = n2 & 63;
        float v;
        if (g == 0)      v = (k < 64) ? wih[j * 64 + k]         : whh[j * 64 + (k - 64)];
        else if (g == 1) v = (k < 64) ? wih[(64 + j) * 64 + k]  : whh[(64 + j) * 64 + (k - 64)];
        else if (g == 2) v = (k < 64) ? wih[(128 + j) * 64 + k] : 0.f;
        else             v = (k < 64) ? 0.f                     : whh[(128 + j) * 64 + (k - 64)];
        W2h[t] = (_Float16)v;
    }
    if (t < 256) {
        int g = t >> 6, j = t & 63;
        float v = (g == 0) ? bih[j] + bhh[j]
                : (g == 1) ? bih[64 + j] + bhh[64 + j]
                : (g == 2) ? bih[128 + j] : bhh[128 + j];
        fbias[t] = v;
    }
}

// ---------------- out0 = relu(x @ lin0_w.T + b) ----------------
__global__ void lin0_kernel(const float* __restrict__ x, const float* __restrict__ w,
                            const float* __restrict__ b, float* __restrict__ hv) {
    int t = blockIdx.x * 256 + threadIdx.x;
    if (t >= NN * 64) return;
    int n = t >> 6, d = t & 63;
    float acc = b[d];
    #pragma unroll
    for (int f = 0; f < NF; f++) acc += x[n * NF + f] * w[d * NF + f];
    hv[t] = fmaxf(acc, 0.f);
}

// ---------------- in-degree ----------------
__global__ void deg_kernel(const int* __restrict__ ei, float* __restrict__ deg) {
    int e = blockIdx.x * 256 + threadIdx.x;
    if (e < EE) atomicAdd(&deg[ei[EE + e]], 1.0f);
}

// ---------------- he16 = fp16(relu(edge_attr @ w1.T + b1)), zero-padded to EPAD ----------------
__global__ void he16_kernel(const float* __restrict__ ea, const float* __restrict__ w1,
                            const float* __restrict__ b1, _Float16* __restrict__ he) {
    int t = blockIdx.x * 256 + threadIdx.x;
    if (t >= EPAD * 128) return;
    int el = t >> 7, h = t & 127;
    float acc = 0.f;
    if (el < EE) {
        const float4 a = *(const float4*)(ea + (size_t)el * 4);
        const float4 w = *(const float4*)(w1 + h * 4);
        acc = fmaxf(b1[h] + a.x * w.x + a.y * w.y + a.z * w.z + a.w * w.w, 0.f);
    }
    he[t] = (_Float16)acc;
}

// ---------------- W2rT[o][i*128+h] = fp16(mlp_w2[(i*64+o)*128 + h]) ----------------
__global__ void w2rt_kernel(const float* __restrict__ w2, _Float16* __restrict__ W2rT) {
    int t = blockIdx.x * 256 + threadIdx.x;
    if (t >= 64 * 8192) return;
    int o = t >> 13, k = t & 8191, i = k >> 7, h = k & 127;
    W2rT[(size_t)o * 8192 + k] = (_Float16)w2[(size_t)(i * 64 + o) * 128 + h];
}

// ---------------- msg GEMM: msg = G @ W2rT^T, G generated in-register ----------------
// Round-10: the verified 134us structure (256-edge tile, frag-order sB, dbuf,
// 1 barrier/i) with the staging path swapped from reg-mediated
// (global_load -> pre[] -> ds_write -> lgkm drain) to DIRECT async DMA:
// __builtin_amdgcn_global_load_lds width=16 (m97 pattern). The LDS dest is already
// the required wave-uniform-base + lane*16B layout. Removes per-i: 4 ds_write_b128
// issues + lgkmcnt drain + the vmcnt wait on pre[] (and 16 VGPRs).
__global__ __launch_bounds__(256, 2) void msg_gemm_kernel(
    const float* __restrict__ hv, const _Float16* __restrict__ he16,
    const _Float16* __restrict__ W2rT, const int* __restrict__ ei,
    float* __restrict__ agg, float* __restrict__ xsum) {
    __shared__ _Float16 sB[2][16 * 64 * 8];   // [frag(nt*4+ks)][lane][8]
    __shared__ _Float16 sXs[256 * 68];        // [edge][i], padded stride 68
    __shared__ int sDst[256];
    const int t = threadIdx.x;
    const int eb = blockIdx.x * 256;
    const int lane = t & 63;
    const int w = t >> 6;
    const int col = lane & 15;
    const int quad = lane >> 4;

    if (t < 256) {
        int e = eb + t;
        sDst[t] = (e < EE) ? ei[EE + e] : 0;
    }
    #pragma unroll 4
    for (int rep = 0; rep < 16; rep++) {
        int idx = rep * 256 + t;
        int el = idx >> 4, d4 = idx & 15;
        int e = eb + el;
        float4 v = {0.f, 0.f, 0.f, 0.f};
        if (e < EE) {
            int src = ei[e];
            v = *(const float4*)(hv + (size_t)src * 64 + d4 * 4);
        }
        half4 h4 = {(_Float16)v.x, (_Float16)v.y, (_Float16)v.z, (_Float16)v.w};
        *(half4*)&sXs[el * 68 + d4 * 4] = h4;
    }

    half8 heReg[4][4];
    #pragma unroll
    for (int mt = 0; mt < 4; mt++) {
        int row = eb + w * 64 + mt * 16 + col;
        #pragma unroll
        for (int p = 0; p < 4; p++)
            heReg[mt][p] = *(const half8*)(he16 + (size_t)row * 128 + p * 32 + quad * 8);
    }

    floatx4 Cacc[4][4];
    #pragma unroll
    for (int mt = 0; mt < 4; mt++)
        #pragma unroll
        for (int nt = 0; nt < 4; nt++)
            Cacc[mt][nt] = (floatx4){0.f, 0.f, 0.f, 0.f};

    // staging via global_load_lds: lane l's 16B from
    //   W2rT[(w*16+col)*8192 + quad*8 + i*128 + rep*32]
    // lands at wave-uniform LDS base sB[buf][(w*4+rep)*512] + l*16B
    // == frag slot ((w*4+rep)*64 + lane)*8 halves -- identical layout to the
    // verified reg-staged version.
    const size_t gbase = (size_t)(w * 16 + col) * 8192 + quad * 8;
    auto STAGE = [&](int buf, int i) {
        #pragma unroll
        for (int rep = 0; rep < 4; rep++) {
            const _Float16* src = W2rT + gbase + (size_t)i * 128 + rep * 32;
            _Float16* dst = &sB[buf][(w * 4 + rep) * 512];   // wave-uniform
            __builtin_amdgcn_global_load_lds(
                (const __attribute__((address_space(1))) void*)src,
                (__attribute__((address_space(3))) void*)dst, 16, 0, 0);
        }
    };

    STAGE(0, 0);
    __syncthreads();   // drains sXs writes + buf0 DMA

    #pragma unroll 1
    for (int i = 0; i < 64; i++) {
        int buf = i & 1;
        if (i < 63) STAGE(buf ^ 1, i + 1);   // async DMA overlaps this i's MFMA
        _Float16 xsx[4];
        #pragma unroll
        for (int mt = 0; mt < 4; mt++)
            xsx[mt] = sXs[(w * 64 + mt * 16 + col) * 68 + i];
        #pragma unroll
        for (int ks = 0; ks < 4; ks++) {
            half8 bfr[4];
            #pragma unroll
            for (int nt = 0; nt < 4; nt++)
                bfr[nt] = *(const half8*)&sB[buf][((nt * 4 + ks) * 64 + lane) * 8];
            #pragma unroll
            for (int mt = 0; mt < 4; mt++) {
                half8 afr = heReg[mt][ks] * xsx[mt];
                #pragma unroll
                for (int nt = 0; nt < 4; nt++)
                    Cacc[mt][nt] = __builtin_amdgcn_mfma_f32_16x16x32_f16(afr, bfr[nt], Cacc[mt][nt], 0, 0, 0);
            }
        }
        __syncthreads();   // all reads of buf done + buf^1 DMA drained
    }

    #pragma unroll
    for (int mt = 0; mt < 4; mt++) {
        #pragma unroll
        for (int r = 0; r < 4; r++) {
            int el = w * 64 + mt * 16 + quad * 4 + r;
            if (eb + el < EE) {
                float* ap = agg + (size_t)sDst[el] * 64 + col;
                #pragma unroll
                for (int nt = 0; nt < 4; nt++)
                    atomicAdd(ap + nt * 16, Cacc[mt][nt][r]);
            }
        }
    }
    #pragma unroll 4
    for (int rep = 0; rep < 64; rep++) {
        int idx = rep * 256 + t;
        int el = idx >> 6, d = idx & 63;
        if (eb + el < EE)
            atomicAdd(&xsum[(size_t)sDst[el] * 64 + d], (float)sXs[el * 68 + d]);
    }
}

// ---------------- fused node update: NNConv epilogue + GRU (MFMA) ----------------
// Also re-zeros agg/xsum after consuming them (saves per-iteration memset dispatches).
__global__ __launch_bounds__(256, 2) void node_fused_kernel(
    const float* __restrict__ hv_in, float* __restrict__ agg,
    float* __restrict__ xsum, const float* __restrict__ deg,
    const _Float16* __restrict__ W1h, const _Float16* __restrict__ W2h,
    const float* __restrict__ fbias, const float* __restrict__ cb,
    float* __restrict__ hv_out) {
    __shared__ _Float16 sA1[64 * 136];  // [node][k]: k<64 hv, k>=64 xsum/deg
    __shared__ _Float16 sA2[64 * 136];  // [node][k]: k<64 m, k>=64 hv
    __shared__ float sH[64 * 68];       // h_old fp32, reused for h_new
    __shared__ float sAgg[64 * 68];     // agg/deg fp32
    const int t = threadIdx.x;
    const int nb = blockIdx.x * 64;
    const int n = t >> 2, part = t & 3;
    {
        int gn = nb + n;
        bool valid = gn < NN;
        float inv = 1.f;
        if (valid) inv = 1.f / fmaxf(deg[gn], 1.f);
        #pragma unroll
        for (int c4 = 0; c4 < 4; c4++) {
            int d0 = part * 16 + c4 * 4;
            float4 hvv = {0.f, 0.f, 0.f, 0.f}, agv = {0.f, 0.f, 0.f, 0.f}, xsv = {0.f, 0.f, 0.f, 0.f};
            if (valid) {
                hvv = *(const float4*)(hv_in + (size_t)gn * 64 + d0);
                agv = *(const float4*)(agg + (size_t)gn * 64 + d0);
                xsv = *(const float4*)(xsum + (size_t)gn * 64 + d0);
            }
            agv.x *= inv; agv.y *= inv; agv.z *= inv; agv.w *= inv;
            xsv.x *= inv; xsv.y *= inv; xsv.z *= inv; xsv.w *= inv;
            half4 hvh = {(_Float16)hvv.x, (_Float16)hvv.y, (_Float16)hvv.z, (_Float16)hvv.w};
            half4 xsh = {(_Float16)xsv.x, (_Float16)xsv.y, (_Float16)xsv.z, (_Float16)xsv.w};
            *(half4*)&sA1[n * 136 + d0] = hvh;
            *(half4*)&sA1[n * 136 + 64 + d0] = xsh;
            *(half4*)&sA2[n * 136 + 64 + d0] = hvh;
            *(float4*)&sH[n * 68 + d0] = hvv;
            *(float4*)&sAgg[n * 68 + d0] = agv;
        }
        // re-zero agg/xsum for the next msg_gemm launch
        if (valid) {
            float4 z = {0.f, 0.f, 0.f, 0.f};
            #pragma unroll
            for (int c4 = 0; c4 < 4; c4++) {
                int d0 = part * 16 + c4 * 4;
                *(float4*)(agg + (size_t)gn * 64 + d0) = z;
                *(float4*)(xsum + (size_t)gn * 64 + d0) = z;
            }
        }
    }
    __syncthreads();

    const int lane = t & 63, w = t >> 6;
    const int col = lane & 15, quad = lane >> 4;

    // ---- stage 1 ----
    floatx4 C1[4];
    #pragma unroll
    for (int nt = 0; nt < 4; nt++) {
        float b = cb[nt * 16 + col];
        C1[nt] = (floatx4){b, b, b, b};
    }
    #pragma unroll
    for (int ks = 0; ks < 4; ks++) {
        half8 a = *(const half8*)&sA1[(w * 16 + col) * 136 + ks * 32 + quad * 8];
        #pragma unroll
        for (int nt = 0; nt < 4; nt++) {
            half8 bfr = *(const half8*)(W1h + (size_t)(nt * 16 + col) * 128 + ks * 32 + quad * 8);
            C1[nt] = __builtin_amdgcn_mfma_f32_16x16x32_f16(a, bfr, C1[nt], 0, 0, 0);
        }
    }
    #pragma unroll
    for (int nt = 0; nt < 4; nt++) {
        #pragma unroll
        for (int r = 0; r < 4; r++) {
            int node = w * 16 + quad * 4 + r;
            int j = nt * 16 + col;
            float m = fmaxf(C1[nt][r] + sAgg[node * 68 + j], 0.f);
            sA2[node * 136 + j] = (_Float16)m;
        }
    }
    __syncthreads();

    // ---- stage 2 ----
    floatx4 C2[16];
    #pragma unroll
    for (int nt2 = 0; nt2 < 16; nt2++) {
        float b = fbias[nt2 * 16 + col];
        C2[nt2] = (floatx4){b, b, b, b};
    }
    #pragma unroll
    for (int ks = 0; ks < 4; ks++) {
        half8 a = *(const half8*)&sA2[(w * 16 + col) * 136 + ks * 32 + quad * 8];
        #pragma unroll
        for (int nt2 = 0; nt2 < 16; nt2++) {
            half8 bfr = *(const half8*)(W2h + (size_t)(nt2 * 16 + col) * 128 + ks * 32 + quad * 8);
            C2[nt2] = __builtin_amdgcn_mfma_f32_16x16x32_f16(a, bfr, C2[nt2], 0, 0, 0);
        }
    }
    float hnew[4][4];
    #pragma unroll
    for (int r = 0; r < 4; r++) {
        int node = w * 16 + quad * 4 + r;
        #pragma unroll
        for (int jt = 0; jt < 4; jt++) {
            int j = jt * 16 + col;
            float rr = 1.f / (1.f + expf(-C2[jt][r]));
            float zz = 1.f / (1.f + expf(-C2[4 + jt][r]));
            float ng = tanhf(C2[8 + jt][r] + rr * C2[12 + jt][r]);
            float hold = sH[node * 68 + j];
            hnew[r][jt] = (1.f - zz) * ng + zz * hold;
        }
    }
    __syncthreads();
    #pragma unroll
    for (int r = 0; r < 4; r++) {
        int node = w * 16 + quad * 4 + r;
        #pragma unroll
        for (int jt = 0; jt < 4; jt++)
            sH[node * 68 + jt * 16 + col] = hnew[r][jt];
    }
    __syncthreads();
    {
        int gn = nb + n;
        if (gn < NN) {
            #pragma unroll
            for (int c4 = 0; c4 < 4; c4++) {
                int d0 = part * 16 + c4 * 4;
                *(float4*)(hv_out + (size_t)gn * 64 + d0) = *(const float4*)&sH[n * 68 + d0];
            }
        }
    }
}

// ---------------- fused Set2Set (3 steps) + readout, one block per graph ----------------
__global__ __launch_bounds__(256) void set2set_kernel(
    const float* __restrict__ hv,
    const float* __restrict__ lihT, const float* __restrict__ lhhT,
    const float* __restrict__ l_bih, const float* __restrict__ l_bhh,
    const float* __restrict__ lin1T, const float* __restrict__ lin1_b,
    const float* __restrict__ lin2_w, const float* __restrict__ lin2_b,
    float* __restrict__ out) {
    __shared__ float outS[25 * 65];
    __shared__ float qs[128], qh[64], qc[64], gat[256], ew[32], aw[32], red[64];
    int g = blockIdx.x;
    int t = threadIdx.x;
    for (int p = t; p < 25 * 64; p += 256) {
        int j = p >> 6, i = p & 63;
        outS[j * 65 + i] = hv[(size_t)(g * 25 + j) * 64 + i];
    }
    if (t < 128) qs[t] = 0.f;
    if (t < 64) { qh[t] = 0.f; qc[t] = 0.f; }
    __syncthreads();
    for (int it = 0; it < 3; it++) {
        float acc = l_bih[t] + l_bhh[t];
        for (int k = 0; k < 128; k++) acc += qs[k] * lihT[k * 256 + t];
        for (int k = 0; k < 64; k++) acc += qh[k] * lhhT[k * 256 + t];
        gat[t] = acc;
        __syncthreads();
        if (t < 64) {
            float ig = 1.f / (1.f + expf(-gat[t]));
            float fg = 1.f / (1.f + expf(-gat[64 + t]));
            float gg = tanhf(gat[128 + t]);
            float og = 1.f / (1.f + expf(-gat[192 + t]));
            float c = fg * qc[t] + ig * gg;
            qc[t] = c;
            qh[t] = og * tanhf(c);
        }
        __syncthreads();
        if (t < 25) {
            float e = 0.f;
            for (int i = 0; i < 64; i++) e += outS[t * 65 + i] * qh[i];
            ew[t] = e;
        }
        __syncthreads();
        if (t == 0) {
            float mx = ew[0];
            for (int j = 1; j < 25; j++) mx = fmaxf(mx, ew[j]);
            float s = 0.f;
            for (int j = 0; j < 25; j++) { float a = expf(ew[j] - mx); aw[j] = a; s += a; }
            float inv = 1.f / s;
            for (int j = 0; j < 25; j++) aw[j] *= inv;
        }
        __syncthreads();
        if (t < 64) {
            float r = 0.f;
            for (int j = 0; j < 25; j++) r += aw[j] * outS[j * 65 + t];
            qs[t] = qh[t];
            qs[64 + t] = r;
        }
        __syncthreads();
    }
    if (t < 64) {
        float y1 = lin1_b[t];
        for (int k = 0; k < 128; k++) y1 += qs[k] * lin1T[k * 64 + t];
        y1 = fmaxf(y1, 0.f);
        red[t] = y1 * lin2_w[t];
    }
    __syncthreads();
    if (t == 0) {
        float y = lin2_b[0];
        for (int i = 0; i < 64; i++) y += red[i];
        out[g] = y;
    }
}

extern "C" void kernel_launch(void* const* d_in, const int* in_sizes, int n_in,
                              void* d_out, int out_size, void* d_ws, size_t ws_size,
                              hipStream_t stream) {
    const float* x        = (const float*)d_in[0];
    const float* ea       = (const float*)d_in[1];
    const int*   ei       = (const int*)  d_in[2];
    const float* lin0_w   = (const float*)d_in[4];
    const float* lin0_b   = (const float*)d_in[5];
    const float* mlp_w1   = (const float*)d_in[6];
    const float* mlp_b1   = (const float*)d_in[7];
    const float* mlp_w2   = (const float*)d_in[8];
    const float* mlp_b2   = (const float*)d_in[9];
    const float* root     = (const float*)d_in[10];
    const float* conv_b   = (const float*)d_in[11];
    const float* gru_wih  = (const float*)d_in[12];
    const float* gru_whh  = (const float*)d_in[13];
    const float* gru_bih  = (const float*)d_in[14];
    const float* gru_bhh  = (const float*)d_in[15];
    const float* lstm_wih = (const float*)d_in[16];
    const float* lstm_whh = (const float*)d_in[17];
    const float* lstm_bih = (const float*)d_in[18];
    const float* lstm_bhh = (const float*)d_in[19];
    const float* lin1_w   = (const float*)d_in[20];
    const float* lin1_b   = (const float*)d_in[21];
    const float* lin2_w   = (const float*)d_in[22];
    const float* lin2_b   = (const float*)d_in[23];
    float* out = (float*)d_out;

    // ---- workspace carve ----
    char* base = (char*)d_ws;
    size_t off = 0;
    auto carve = [&](size_t bytes) -> void* {
        void* r = base + off;
        off = (off + bytes + 255) & ~(size_t)255;
        return r;
    };
    float* hv   = (float*)carve((size_t)NN * 64 * 4);
    float* agg  = (float*)carve((size_t)NN * 64 * 4);   // agg+xsum adjacent: one memset
    float* xsum = (float*)carve((size_t)NN * 64 * 4);
    float* deg  = (float*)carve((size_t)NN * 4);
    float* lihT = (float*)carve(128 * 256 * 4);
    float* lhhT = (float*)carve(64 * 256 * 4);
    float* l1T  = (float*)carve(128 * 64 * 4);
    float* fbias = (float*)carve(256 * 4);
    _Float16* he16 = (_Float16*)carve((size_t)EPAD * 128 * 2);
    _Float16* W2rT = (_Float16*)carve((size_t)64 * 8192 * 2);
    _Float16* W1h  = (_Float16*)carve((size_t)64 * 128 * 2);
    _Float16* W2h  = (_Float16*)carve((size_t)256 * 128 * 2);

    // ---- preamble ----
    hipMemsetAsync(deg, 0, (size_t)NN * 4, stream);
    hipMemsetAsync(agg, 0, (size_t)NN * 64 * 4 * 2, stream);  // agg + xsum (adjacent)
    transpose_kernel<<<128, 256, 0, stream>>>(lstm_wih, lstm_whh, lin1_w, lihT, lhhT, l1T);
    prep_gru_kernel<<<128, 256, 0, stream>>>(root, mlp_b2, gru_wih, gru_whh, gru_bih, gru_bhh,
                                             W1h, W2h, fbias);
    lin0_kernel<<<(NN * 64 + 255) / 256, 256, 0, stream>>>(x, lin0_w, lin0_b, hv);
    deg_kernel<<<(EE + 255) / 256, 256, 0, stream>>>(ei, deg);
    he16_kernel<<<(EPAD * 128 + 255) / 256, 256, 0, stream>>>(ea, mlp_w1, mlp_b1, he16);
    w2rt_kernel<<<(64 * 8192 + 255) / 256, 256, 0, stream>>>(mlp_w2, W2rT);

    // ---- 3 message-passing + GRU iterations (node_fused re-zeros agg/xsum) ----
    for (int it = 0; it < 3; it++) {
        msg_gemm_kernel<<<EPAD / 256, 256, 0, stream>>>(hv, he16, W2rT, ei, agg, xsum);
        node_fused_kernel<<<(NN + 63) / 64, 256, 0, stream>>>(hv, agg, xsum, deg,
                                                              W1h, W2h, fbias, conv_b, hv);
    }

    // ---- Set2Set + readout ----
    set2set_kernel<<<BB, 256, 0, stream>>>(hv, lihT, lhhT, lstm_bih, lstm_bhh,
                                           l1T, lin1_b, lin2_w, lin2_b, out);
}

// Round 6
// 812.511 us; speedup vs baseline: 1.4303x; 1.0025x over previous
//
#include <hip/hip_runtime.h>
#include <hip/hip_bf16.h>

#define NN 50000
#define EE 100000
#define BB 2000
#define DIM 64
#define NF 14
#define EF 4
#define HID 128
#define EPAD 100096  // 391 * 256

typedef __attribute__((ext_vector_type(8))) _Float16 half8;   // 4 VGPRs
typedef __attribute__((ext_vector_type(4))) _Float16 half4;
typedef __attribute__((ext_vector_type(4))) float floatx4;    // MFMA C/D

__device__ __forceinline__ float rcp_fast(float x) { return __builtin_amdgcn_rcpf(x); }
__device__ __forceinline__ float sig_fast(float x) { return rcp_fast(1.f + __expf(-x)); }
__device__ __forceinline__ float tanh_fast(float x) {
    float e = __expf(2.f * x);
    return 1.f - 2.f * rcp_fast(e + 1.f);
}

// ---------------- fused preamble: w2rt + transposes + gru-prep + he16(+deg) + lin0 ----
// All sections write disjoint outputs; guarded by global thread ranges.
// grid = EPAD*16/256 = 6256 blocks.
__global__ void prep_fused_kernel(
    const float* __restrict__ x, const float* __restrict__ lin0_w,
    const float* __restrict__ lin0_b, float* __restrict__ hv,
    const float* __restrict__ ea, const float* __restrict__ w1,
    const float* __restrict__ b1, _Float16* __restrict__ he,
    const int* __restrict__ ei, float* __restrict__ deg,
    const float* __restrict__ w2, _Float16* __restrict__ W2rT,
    const float* __restrict__ lih, const float* __restrict__ lhh,
    const float* __restrict__ l1, float* __restrict__ lihT,
    float* __restrict__ lhhT, float* __restrict__ l1T,
    const float* __restrict__ root, const float* __restrict__ b2,
    const float* __restrict__ gwih, const float* __restrict__ gwhh,
    const float* __restrict__ gbih, const float* __restrict__ gbhh,
    _Float16* __restrict__ W1h, _Float16* __restrict__ W2h,
    float* __restrict__ fbias) {
    int t = blockIdx.x * 256 + threadIdx.x;

    // --- he16 (vectorized, 8 h/thread) + deg atomic; covers all t ---
    {
        int el = t >> 4, hc = t & 15;
        if (el < EPAD) {
            half8 o8 = {0, 0, 0, 0, 0, 0, 0, 0};
            if (el < EE) {
                const float4 a = *(const float4*)(ea + (size_t)el * 4);
                #pragma unroll
                for (int j = 0; j < 8; j++) {
                    int h = hc * 8 + j;
                    const float4 w = *(const float4*)(w1 + h * 4);
                    float acc = fmaxf(b1[h] + a.x * w.x + a.y * w.y + a.z * w.z + a.w * w.w, 0.f);
                    o8[j] = (_Float16)acc;
                }
                if (hc == 0) atomicAdd(&deg[ei[EE + el]], 1.0f);
            }
            *(half8*)(he + (size_t)el * 128 + hc * 8) = o8;
        }
    }
    // --- lin0 (vectorized, 8 d/thread): t < NN*8 ---
    if (t < NN * 8) {
        int n = t >> 3, dc = t & 7;
        float xv[NF];
        #pragma unroll
        for (int f = 0; f < NF; f++) xv[f] = x[(size_t)n * NF + f];
        float o[8];
        #pragma unroll
        for (int j = 0; j < 8; j++) {
            int d = dc * 8 + j;
            float acc = lin0_b[d];
            #pragma unroll
            for (int f = 0; f < NF; f++) acc += xv[f] * lin0_w[d * NF + f];
            o[j] = fmaxf(acc, 0.f);
        }
        *(float4*)(hv + (size_t)n * 64 + dc * 8)     = make_float4(o[0], o[1], o[2], o[3]);
        *(float4*)(hv + (size_t)n * 64 + dc * 8 + 4) = make_float4(o[4], o[5], o[6], o[7]);
    }
    // --- w2rt (vectorized, 8 k/thread): t < 64*1024 ---
    if (t < 64 * 1024) {
        int o = t >> 10, kc = t & 1023;
        int k0 = kc * 8, i = k0 >> 7, h0 = k0 & 127;
        const float* src = w2 + (size_t)(i * 64 + o) * 128 + h0;
        const float4 a = *(const float4*)src;
        const float4 b = *(const float4*)(src + 4);
        half8 r = {(_Float16)a.x, (_Float16)a.y, (_Float16)a.z, (_Float16)a.w,
                   (_Float16)b.x, (_Float16)b.y, (_Float16)b.z, (_Float16)b.w};
        *(half8*)(W2rT + (size_t)o * 8192 + k0) = r;
    }
    // --- set2set weight transposes: t < 32768 ---
    if (t < 256 * 128) { int j = t / 128, k = t % 128; lihT[k * 256 + j] = lih[t]; }
    if (t < 256 * 64) { int j = t / 64, k = t % 64; lhhT[k * 256 + j] = lhh[t]; }
    if (t < 64 * 128) { int d = t / 128, k = t % 128; l1T[k * 64 + d] = l1[t]; }
    // --- gru weight prep: t < 32768 ---
    if (t < 64 * 128) {
        int n = t >> 7, k = t & 127;
        W1h[t] = (_Float16)(k < 64 ? root[k * 64 + n] : b2[(size_t)(k - 64) * 64 + n]);
    }
    if (t < 256 * 128) {
        int n2 = t >> 7, k = t & 127;
        int g = n2 >> 6, j = n2 & 63;
        float v;
        if (g == 0)      v = (k < 64) ? gwih[j * 64 + k]         : gwhh[j * 64 + (k - 64)];
        else if (g == 1) v = (k < 64) ? gwih[(64 + j) * 64 + k]  : gwhh[(64 + j) * 64 + (k - 64)];
        else if (g == 2) v = (k < 64) ? gwih[(128 + j) * 64 + k] : 0.f;
        else             v = (k < 64) ? 0.f                      : gwhh[(128 + j) * 64 + (k - 64)];
        W2h[t] = (_Float16)v;
    }
    if (t < 256) {
        int g = t >> 6, j = t & 63;
        float v = (g == 0) ? gbih[j] + gbhh[j]
                : (g == 1) ? gbih[64 + j] + gbhh[64 + j]
                : (g == 2) ? gbih[128 + j] : gbhh[128 + j];
        fbias[t] = v;
    }
}

// ---------------- msg GEMM: msg = G @ W2rT^T, G generated in-register ----------------
// Round-11: the verified 134us kernel (256-edge tile, frag-order sB, reg-staged dbuf,
// 1 barrier/slice) with SPLIT-K x2: blockIdx&1 selects 32 of the 64 i-slices.
// agg is atomically accumulated so K-partials are free; xsum epilogue only on ki==0
// (ki==1 stages only sXs columns 32..63). Grid 391 -> 782 blocks: converts the 76%
// one-shot packing (391 blocks over 512 resident slots, 121 CUs idle half the
// dispatch) into work-conserving ~76%-time packing with a short tail.
__global__ __launch_bounds__(256, 2) void msg_gemm_kernel(
    const float* __restrict__ hv, const _Float16* __restrict__ he16,
    const _Float16* __restrict__ W2rT, const int* __restrict__ ei,
    float* __restrict__ agg, float* __restrict__ xsum) {
    __shared__ _Float16 sB[2][16 * 64 * 8];   // [frag(nt*4+ks)][lane][8]
    __shared__ _Float16 sXs[256 * 68];        // [edge][i], padded stride 68
    __shared__ int sDst[256];
    const int t = threadIdx.x;
    const int tile = blockIdx.x >> 1;
    const int ki = blockIdx.x & 1;
    const int eb = tile * 256;
    const int base = ki * 32;      // first i-slice of this block
    const int lane = t & 63;
    const int w = t >> 6;
    const int col = lane & 15;
    const int quad = lane >> 4;

    if (t < 256) {
        int e = eb + t;
        sDst[t] = (e < EE) ? ei[EE + e] : 0;
    }
    if (ki == 0) {
        // full sXs (columns 0..63): needed for slices 0..31 AND the xsum epilogue
        #pragma unroll 4
        for (int rep = 0; rep < 16; rep++) {
            int idx = rep * 256 + t;
            int el = idx >> 4, d4 = idx & 15;
            int e = eb + el;
            float4 v = {0.f, 0.f, 0.f, 0.f};
            if (e < EE) {
                int src = ei[e];
                v = *(const float4*)(hv + (size_t)src * 64 + d4 * 4);
            }
            half4 h4 = {(_Float16)v.x, (_Float16)v.y, (_Float16)v.z, (_Float16)v.w};
            *(half4*)&sXs[el * 68 + d4 * 4] = h4;
        }
    } else {
        // columns 32..63 only (d4 in [8,16))
        #pragma unroll 4
        for (int rep = 0; rep < 8; rep++) {
            int idx = rep * 256 + t;
            int el = idx >> 3, d4 = 8 + (idx & 7);
            int e = eb + el;
            float4 v = {0.f, 0.f, 0.f, 0.f};
            if (e < EE) {
                int src = ei[e];
                v = *(const float4*)(hv + (size_t)src * 64 + d4 * 4);
            }
            half4 h4 = {(_Float16)v.x, (_Float16)v.y, (_Float16)v.z, (_Float16)v.w};
            *(half4*)&sXs[el * 68 + d4 * 4] = h4;
        }
    }

    half8 heReg[4][4];
    #pragma unroll
    for (int mt = 0; mt < 4; mt++) {
        int row = eb + w * 64 + mt * 16 + col;
        #pragma unroll
        for (int p = 0; p < 4; p++)
            heReg[mt][p] = *(const half8*)(he16 + (size_t)row * 128 + p * 32 + quad * 8);
    }

    floatx4 Cacc[4][4];
    #pragma unroll
    for (int mt = 0; mt < 4; mt++)
        #pragma unroll
        for (int nt = 0; nt < 4; nt++)
            Cacc[mt][nt] = (floatx4){0.f, 0.f, 0.f, 0.f};

    const size_t gbase = (size_t)(w * 16 + col) * 8192 + quad * 8;
    half8 pre[4];
    {
        #pragma unroll
        for (int rep = 0; rep < 4; rep++)
            pre[rep] = *(const half8*)(W2rT + gbase + (size_t)base * 128 + rep * 32);
        #pragma unroll
        for (int rep = 0; rep < 4; rep++)
            *(half8*)&sB[0][((w * 4 + rep) * 64 + lane) * 8] = pre[rep];
    }
    __syncthreads();

    #pragma unroll 1
    for (int ii = 0; ii < 32; ii++) {
        int buf = ii & 1;
        if (ii < 31) {
            #pragma unroll
            for (int rep = 0; rep < 4; rep++)
                pre[rep] = *(const half8*)(W2rT + gbase + (size_t)(base + ii + 1) * 128 + rep * 32);
        }
        _Float16 xsx[4];
        #pragma unroll
        for (int mt = 0; mt < 4; mt++)
            xsx[mt] = sXs[(w * 64 + mt * 16 + col) * 68 + base + ii];
        #pragma unroll
        for (int ks = 0; ks < 4; ks++) {
            half8 bfr[4];
            #pragma unroll
            for (int nt = 0; nt < 4; nt++)
                bfr[nt] = *(const half8*)&sB[buf][((nt * 4 + ks) * 64 + lane) * 8];
            #pragma unroll
            for (int mt = 0; mt < 4; mt++) {
                half8 afr = heReg[mt][ks] * xsx[mt];
                #pragma unroll
                for (int nt = 0; nt < 4; nt++)
                    Cacc[mt][nt] = __builtin_amdgcn_mfma_f32_16x16x32_f16(afr, bfr[nt], Cacc[mt][nt], 0, 0, 0);
            }
        }
        if (ii < 31) {
            #pragma unroll
            for (int rep = 0; rep < 4; rep++)
                *(half8*)&sB[buf ^ 1][((w * 4 + rep) * 64 + lane) * 8] = pre[rep];
        }
        __syncthreads();
    }

    #pragma unroll
    for (int mt = 0; mt < 4; mt++) {
        #pragma unroll
        for (int r = 0; r < 4; r++) {
            int el = w * 64 + mt * 16 + quad * 4 + r;
            if (eb + el < EE) {
                float* ap = agg + (size_t)sDst[el] * 64 + col;
                #pragma unroll
                for (int nt = 0; nt < 4; nt++)
                    atomicAdd(ap + nt * 16, Cacc[mt][nt][r]);
            }
        }
    }
    if (ki == 0) {
        #pragma unroll 4
        for (int rep = 0; rep < 64; rep++) {
            int idx = rep * 256 + t;
            int el = idx >> 6, d = idx & 63;
            if (eb + el < EE)
                atomicAdd(&xsum[(size_t)sDst[el] * 64 + d], (float)sXs[el * 68 + d]);
        }
    }
}

// ---------------- fused node update: NNConv epilogue + GRU (MFMA) ----------------
// Also re-zeros agg/xsum after consuming them (saves per-iteration memset dispatches).
__global__ __launch_bounds__(256, 2) void node_fused_kernel(
    const float* __restrict__ hv_in, float* __restrict__ agg,
    float* __restrict__ xsum, const float* __restrict__ deg,
    const _Float16* __restrict__ W1h, const _Float16* __restrict__ W2h,
    const float* __restrict__ fbias, const float* __restrict__ cb,
    float* __restrict__ hv_out) {
    __shared__ _Float16 sA1[64 * 136];  // [node][k]: k<64 hv, k>=64 xsum/deg
    __shared__ _Float16 sA2[64 * 136];  // [node][k]: k<64 m, k>=64 hv
    __shared__ float sH[64 * 68];       // h_old fp32, reused for h_new
    __shared__ float sAgg[64 * 68];     // agg/deg fp32
    const int t = threadIdx.x;
    const int nb = blockIdx.x * 64;
    const int n = t >> 2, part = t & 3;
    {
        int gn = nb + n;
        bool valid = gn < NN;
        float inv = 1.f;
        if (valid) inv = 1.f / fmaxf(deg[gn], 1.f);
        #pragma unroll
        for (int c4 = 0; c4 < 4; c4++) {
            int d0 = part * 16 + c4 * 4;
            float4 hvv = {0.f, 0.f, 0.f, 0.f}, agv = {0.f, 0.f, 0.f, 0.f}, xsv = {0.f, 0.f, 0.f, 0.f};
            if (valid) {
                hvv = *(const float4*)(hv_in + (size_t)gn * 64 + d0);
                agv = *(const float4*)(agg + (size_t)gn * 64 + d0);
                xsv = *(const float4*)(xsum + (size_t)gn * 64 + d0);
            }
            agv.x *= inv; agv.y *= inv; agv.z *= inv; agv.w *= inv;
            xsv.x *= inv; xsv.y *= inv; xsv.z *= inv; xsv.w *= inv;
            half4 hvh = {(_Float16)hvv.x, (_Float16)hvv.y, (_Float16)hvv.z, (_Float16)hvv.w};
            half4 xsh = {(_Float16)xsv.x, (_Float16)xsv.y, (_Float16)xsv.z, (_Float16)xsv.w};
            *(half4*)&sA1[n * 136 + d0] = hvh;
            *(half4*)&sA1[n * 136 + 64 + d0] = xsh;
            *(half4*)&sA2[n * 136 + 64 + d0] = hvh;
            *(float4*)&sH[n * 68 + d0] = hvv;
            *(float4*)&sAgg[n * 68 + d0] = agv;
        }
        // re-zero agg/xsum for the next msg_gemm launch
        if (valid) {
            float4 z = {0.f, 0.f, 0.f, 0.f};
            #pragma unroll
            for (int c4 = 0; c4 < 4; c4++) {
                int d0 = part * 16 + c4 * 4;
                *(float4*)(agg + (size_t)gn * 64 + d0) = z;
                *(float4*)(xsum + (size_t)gn * 64 + d0) = z;
            }
        }
    }
    __syncthreads();

    const int lane = t & 63, w = t >> 6;
    const int col = lane & 15, quad = lane >> 4;

    // ---- stage 1 ----
    floatx4 C1[4];
    #pragma unroll
    for (int nt = 0; nt < 4; nt++) {
        float b = cb[nt * 16 + col];
        C1[nt] = (floatx4){b, b, b, b};
    }
    #pragma unroll
    for (int ks = 0; ks < 4; ks++) {
        half8 a = *(const half8*)&sA1[(w * 16 + col) * 136 + ks * 32 + quad * 8];
        #pragma unroll
        for (int nt = 0; nt < 4; nt++) {
            half8 bfr = *(const half8*)(W1h + (size_t)(nt * 16 + col) * 128 + ks * 32 + quad * 8);
            C1[nt] = __builtin_amdgcn_mfma_f32_16x16x32_f16(a, bfr, C1[nt], 0, 0, 0);
        }
    }
    #pragma unroll
    for (int nt = 0; nt < 4; nt++) {
        #pragma unroll
        for (int r = 0; r < 4; r++) {
            int node = w * 16 + quad * 4 + r;
            int j = nt * 16 + col;
            float m = fmaxf(C1[nt][r] + sAgg[node * 68 + j], 0.f);
            sA2[node * 136 + j] = (_Float16)m;
        }
    }
    __syncthreads();

    // ---- stage 2 ----
    floatx4 C2[16];
    #pragma unroll
    for (int nt2 = 0; nt2 < 16; nt2++) {
        float b = fbias[nt2 * 16 + col];
        C2[nt2] = (floatx4){b, b, b, b};
    }
    #pragma unroll
    for (int ks = 0; ks < 4; ks++) {
        half8 a = *(const half8*)&sA2[(w * 16 + col) * 136 + ks * 32 + quad * 8];
        #pragma unroll
        for (int nt2 = 0; nt2 < 16; nt2++) {
            half8 bfr = *(const half8*)(W2h + (size_t)(nt2 * 16 + col) * 128 + ks * 32 + quad * 8);
            C2[nt2] = __builtin_amdgcn_mfma_f32_16x16x32_f16(a, bfr, C2[nt2], 0, 0, 0);
        }
    }
    float hnew[4][4];
    #pragma unroll
    for (int r = 0; r < 4; r++) {
        int node = w * 16 + quad * 4 + r;
        #pragma unroll
        for (int jt = 0; jt < 4; jt++) {
            int j = jt * 16 + col;
            float rr = sig_fast(C2[jt][r]);
            float zz = sig_fast(C2[4 + jt][r]);
            float ng = tanh_fast(C2[8 + jt][r] + rr * C2[12 + jt][r]);
            float hold = sH[node * 68 + j];
            hnew[r][jt] = (1.f - zz) * ng + zz * hold;
        }
    }
    __syncthreads();
    #pragma unroll
    for (int r = 0; r < 4; r++) {
        int node = w * 16 + quad * 4 + r;
        #pragma unroll
        for (int jt = 0; jt < 4; jt++)
            sH[node * 68 + jt * 16 + col] = hnew[r][jt];
    }
    __syncthreads();
    {
        int gn = nb + n;
        if (gn < NN) {
            #pragma unroll
            for (int c4 = 0; c4 < 4; c4++) {
                int d0 = part * 16 + c4 * 4;
                *(float4*)(hv_out + (size_t)gn * 64 + d0) = *(const float4*)&sH[n * 68 + d0];
            }
        }
    }
}

// ---------------- fused Set2Set (3 steps) + readout, one block per graph ----------------
__global__ __launch_bounds__(256) void set2set_kernel(
    const float* __restrict__ hv,
    const float* __restrict__ lihT, const float* __restrict__ lhhT,
    const float* __restrict__ l_bih, const float* __restrict__ l_bhh,
    const float* __restrict__ lin1T, const float* __restrict__ lin1_b,
    const float* __restrict__ lin2_w, const float* __restrict__ lin2_b,
    float* __restrict__ out) {
    __shared__ float outS[25 * 65];
    __shared__ float qs[128], qh[64], qc[64], gat[256], ew[32], aw[32], red[64];
    int g = blockIdx.x;
    int t = threadIdx.x;
    for (int p = t; p < 25 * 64; p += 256) {
        int j = p >> 6, i = p & 63;
        outS[j * 65 + i] = hv[(size_t)(g * 25 + j) * 64 + i];
    }
    if (t < 128) qs[t] = 0.f;
    if (t < 64) { qh[t] = 0.f; qc[t] = 0.f; }
    __syncthreads();
    for (int it = 0; it < 3; it++) {
        float acc = l_bih[t] + l_bhh[t];
        for (int k = 0; k < 128; k++) acc += qs[k] * lihT[k * 256 + t];
        for (int k = 0; k < 64; k++) acc += qh[k] * lhhT[k * 256 + t];
        gat[t] = acc;
        __syncthreads();
        if (t < 64) {
            float ig = sig_fast(gat[t]);
            float fg = sig_fast(gat[64 + t]);
            float gg = tanh_fast(gat[128 + t]);
            float og = sig_fast(gat[192 + t]);
            float c = fg * qc[t] + ig * gg;
            qc[t] = c;
            qh[t] = og * tanh_fast(c);
        }
        __syncthreads();
        if (t < 25) {
            float e = 0.f;
            for (int i = 0; i < 64; i++) e += outS[t * 65 + i] * qh[i];
            ew[t] = e;
        }
        __syncthreads();
        if (t == 0) {
            float mx = ew[0];
            for (int j = 1; j < 25; j++) mx = fmaxf(mx, ew[j]);
            float s = 0.f;
            for (int j = 0; j < 25; j++) { float a = __expf(ew[j] - mx); aw[j] = a; s += a; }
            float inv = rcp_fast(s);
            for (int j = 0; j < 25; j++) aw[j] *= inv;
        }
        __syncthreads();
        if (t < 64) {
            float r = 0.f;
            for (int j = 0; j < 25; j++) r += aw[j] * outS[j * 65 + t];
            qs[t] = qh[t];
            qs[64 + t] = r;
        }
        __syncthreads();
    }
    if (t < 64) {
        float y1 = lin1_b[t];
        for (int k = 0; k < 128; k++) y1 += qs[k] * lin1T[k * 64 + t];
        y1 = fmaxf(y1, 0.f);
        red[t] = y1 * lin2_w[t];
    }
    __syncthreads();
    if (t == 0) {
        float y = lin2_b[0];
        for (int i = 0; i < 64; i++) y += red[i];
        out[g] = y;
    }
}

extern "C" void kernel_launch(void* const* d_in, const int* in_sizes, int n_in,
                              void* d_out, int out_size, void* d_ws, size_t ws_size,
                              hipStream_t stream) {
    const float* x        = (const float*)d_in[0];
    const float* ea       = (const float*)d_in[1];
    const int*   ei       = (const int*)  d_in[2];
    const float* lin0_w   = (const float*)d_in[4];
    const float* lin0_b   = (const float*)d_in[5];
    const float* mlp_w1   = (const float*)d_in[6];
    const float* mlp_b1   = (const float*)d_in[7];
    const float* mlp_w2   = (const float*)d_in[8];
    const float* mlp_b2   = (const float*)d_in[9];
    const float* root     = (const float*)d_in[10];
    const float* conv_b   = (const float*)d_in[11];
    const float* gru_wih  = (const float*)d_in[12];
    const float* gru_whh  = (const float*)d_in[13];
    const float* gru_bih  = (const float*)d_in[14];
    const float* gru_bhh  = (const float*)d_in[15];
    const float* lstm_wih = (const float*)d_in[16];
    const float* lstm_whh = (const float*)d_in[17];
    const float* lstm_bih = (const float*)d_in[18];
    const float* lstm_bhh = (const float*)d_in[19];
    const float* lin1_w   = (const float*)d_in[20];
    const float* lin1_b   = (const float*)d_in[21];
    const float* lin2_w   = (const float*)d_in[22];
    const float* lin2_b   = (const float*)d_in[23];
    float* out = (float*)d_out;

    // ---- workspace carve ----
    char* base = (char*)d_ws;
    size_t off = 0;
    auto carve = [&](size_t bytes) -> void* {
        void* r = base + off;
        off = (off + bytes + 255) & ~(size_t)255;
        return r;
    };
    float* hv   = (float*)carve((size_t)NN * 64 * 4);
    float* agg  = (float*)carve((size_t)NN * 64 * 4);   // agg+xsum+deg adjacent: one memset
    float* xsum = (float*)carve((size_t)NN * 64 * 4);
    float* deg  = (float*)carve((size_t)NN * 4);
    float* lihT = (float*)carve(128 * 256 * 4);
    float* lhhT = (float*)carve(64 * 256 * 4);
    float* l1T  = (float*)carve(128 * 64 * 4);
    float* fbias = (float*)carve(256 * 4);
    _Float16* he16 = (_Float16*)carve((size_t)EPAD * 128 * 2);
    _Float16* W2rT = (_Float16*)carve((size_t)64 * 8192 * 2);
    _Float16* W1h  = (_Float16*)carve((size_t)64 * 128 * 2);
    _Float16* W2h  = (_Float16*)carve((size_t)256 * 128 * 2);

    // ---- preamble: one memset (agg+xsum+deg contiguous) + one fused prep kernel ----
    hipMemsetAsync(agg, 0, (size_t)NN * 64 * 4 * 2 + (size_t)NN * 4, stream);
    prep_fused_kernel<<<EPAD * 16 / 256, 256, 0, stream>>>(
        x, lin0_w, lin0_b, hv,
        ea, mlp_w1, mlp_b1, he16, ei, deg,
        mlp_w2, W2rT,
        lstm_wih, lstm_whh, lin1_w, lihT, lhhT, l1T,
        root, mlp_b2, gru_wih, gru_whh, gru_bih, gru_bhh,
        W1h, W2h, fbias);

    // ---- 3 message-passing + GRU iterations (node_fused re-zeros agg/xsum) ----
    for (int it = 0; it < 3; it++) {
        msg_gemm_kernel<<<(EPAD / 256) * 2, 256, 0, stream>>>(hv, he16, W2rT, ei, agg, xsum);
        node_fused_kernel<<<(NN + 63) / 64, 256, 0, stream>>>(hv, agg, xsum, deg,
                                                              W1h, W2h, fbias, conv_b, hv);
    }

    // ---- Set2Set + readout ----
    set2set_kernel<<<BB, 256, 0, stream>>>(hv, lihT, lhhT, lstm_bih, lstm_bhh,
                                           l1T, lin1_b, lin2_w, lin2_b, out);
}

// Round 7
// 768.454 us; speedup vs baseline: 1.5123x; 1.0573x over previous
//
#include <hip/hip_runtime.h>
#include <hip/hip_bf16.h>

#define NN 50000
#define EE 100000
#define BB 2000
#define DIM 64
#define NF 14
#define EF 4
#define HID 128
#define EPAD 100096   // 391 * 256   (v1 tile grid)
#define EPAD2 100352  // 196 * 512   (v2 tile grid; he16 padded to this)

typedef __attribute__((ext_vector_type(8))) _Float16 half8;   // 4 VGPRs
typedef __attribute__((ext_vector_type(4))) _Float16 half4;
typedef __attribute__((ext_vector_type(4))) float floatx4;    // MFMA C/D

__device__ __forceinline__ float rcp_fast(float x) { return __builtin_amdgcn_rcpf(x); }
__device__ __forceinline__ float sig_fast(float x) { return rcp_fast(1.f + __expf(-x)); }
__device__ __forceinline__ float tanh_fast(float x) {
    float e = __expf(2.f * x);
    return 1.f - 2.f * rcp_fast(e + 1.f);
}

// ---------------- fused preamble: w2rt + transposes + gru-prep + he16(+deg) + lin0 ----
// grid = EPAD2*16/256 = 6272 blocks.
__global__ void prep_fused_kernel(
    const float* __restrict__ x, const float* __restrict__ lin0_w,
    const float* __restrict__ lin0_b, float* __restrict__ hv,
    const float* __restrict__ ea, const float* __restrict__ w1,
    const float* __restrict__ b1, _Float16* __restrict__ he,
    const int* __restrict__ ei, float* __restrict__ deg,
    const float* __restrict__ w2, _Float16* __restrict__ W2rT,
    const float* __restrict__ lih, const float* __restrict__ lhh,
    const float* __restrict__ l1, float* __restrict__ lihT,
    float* __restrict__ lhhT, float* __restrict__ l1T,
    const float* __restrict__ root, const float* __restrict__ b2,
    const float* __restrict__ gwih, const float* __restrict__ gwhh,
    const float* __restrict__ gbih, const float* __restrict__ gbhh,
    _Float16* __restrict__ W1h, _Float16* __restrict__ W2h,
    float* __restrict__ fbias) {
    int t = blockIdx.x * 256 + threadIdx.x;

    // --- he16 (vectorized, 8 h/thread) + deg atomic; rows >= EE zero-padded to EPAD2 ---
    {
        int el = t >> 4, hc = t & 15;
        if (el < EPAD2) {
            half8 o8 = {0, 0, 0, 0, 0, 0, 0, 0};
            if (el < EE) {
                const float4 a = *(const float4*)(ea + (size_t)el * 4);
                #pragma unroll
                for (int j = 0; j < 8; j++) {
                    int h = hc * 8 + j;
                    const float4 w = *(const float4*)(w1 + h * 4);
                    float acc = fmaxf(b1[h] + a.x * w.x + a.y * w.y + a.z * w.z + a.w * w.w, 0.f);
                    o8[j] = (_Float16)acc;
                }
                if (hc == 0) atomicAdd(&deg[ei[EE + el]], 1.0f);
            }
            *(half8*)(he + (size_t)el * 128 + hc * 8) = o8;
        }
    }
    // --- lin0 (vectorized, 8 d/thread): t < NN*8 ---
    if (t < NN * 8) {
        int n = t >> 3, dc = t & 7;
        float xv[NF];
        #pragma unroll
        for (int f = 0; f < NF; f++) xv[f] = x[(size_t)n * NF + f];
        float o[8];
        #pragma unroll
        for (int j = 0; j < 8; j++) {
            int d = dc * 8 + j;
            float acc = lin0_b[d];
            #pragma unroll
            for (int f = 0; f < NF; f++) acc += xv[f] * lin0_w[d * NF + f];
            o[j] = fmaxf(acc, 0.f);
        }
        *(float4*)(hv + (size_t)n * 64 + dc * 8)     = make_float4(o[0], o[1], o[2], o[3]);
        *(float4*)(hv + (size_t)n * 64 + dc * 8 + 4) = make_float4(o[4], o[5], o[6], o[7]);
    }
    // --- w2rt (vectorized, 8 k/thread): t < 64*1024 ---
    if (t < 64 * 1024) {
        int o = t >> 10, kc = t & 1023;
        int k0 = kc * 8, i = k0 >> 7, h0 = k0 & 127;
        const float* src = w2 + (size_t)(i * 64 + o) * 128 + h0;
        const float4 a = *(const float4*)src;
        const float4 b = *(const float4*)(src + 4);
        half8 r = {(_Float16)a.x, (_Float16)a.y, (_Float16)a.z, (_Float16)a.w,
                   (_Float16)b.x, (_Float16)b.y, (_Float16)b.z, (_Float16)b.w};
        *(half8*)(W2rT + (size_t)o * 8192 + k0) = r;
    }
    // --- set2set weight transposes ---
    if (t < 256 * 128) { int j = t / 128, k = t % 128; lihT[k * 256 + j] = lih[t]; }
    if (t < 256 * 64) { int j = t / 64, k = t % 64; lhhT[k * 256 + j] = lhh[t]; }
    if (t < 64 * 128) { int d = t / 128, k = t % 128; l1T[k * 64 + d] = l1[t]; }
    // --- gru weight prep ---
    if (t < 64 * 128) {
        int n = t >> 7, k = t & 127;
        W1h[t] = (_Float16)(k < 64 ? root[k * 64 + n] : b2[(size_t)(k - 64) * 64 + n]);
    }
    if (t < 256 * 128) {
        int n2 = t >> 7, k = t & 127;
        int g = n2 >> 6, j = n2 & 63;
        float v;
        if (g == 0)      v = (k < 64) ? gwih[j * 64 + k]         : gwhh[j * 64 + (k - 64)];
        else if (g == 1) v = (k < 64) ? gwih[(64 + j) * 64 + k]  : gwhh[(64 + j) * 64 + (k - 64)];
        else if (g == 2) v = (k < 64) ? gwih[(128 + j) * 64 + k] : 0.f;
        else             v = (k < 64) ? 0.f                      : gwhh[(128 + j) * 64 + (k - 64)];
        W2h[t] = (_Float16)v;
    }
    if (t < 256) {
        int g = t >> 6, j = t & 63;
        float v = (g == 0) ? gbih[j] + gbhh[j]
                : (g == 1) ? gbih[64 + j] + gbhh[64 + j]
                : (g == 2) ? gbih[128 + j] : gbhh[128 + j];
        fbias[t] = v;
    }
}

// ---------------- msg GEMM v1: the verified 134us kernel (byte-identical) -------------
__global__ __launch_bounds__(256, 2) void msg_gemm_kernel(
    const float* __restrict__ hv, const _Float16* __restrict__ he16,
    const _Float16* __restrict__ W2rT, const int* __restrict__ ei,
    float* __restrict__ agg, float* __restrict__ xsum) {
    __shared__ _Float16 sB[2][16 * 64 * 8];   // [frag(nt*4+ks)][lane][8]
    __shared__ _Float16 sXs[256 * 68];        // [edge][i], padded stride 68
    __shared__ int sDst[256];
    const int t = threadIdx.x;
    const int eb = blockIdx.x * 256;
    const int lane = t & 63;
    const int w = t >> 6;
    const int col = lane & 15;
    const int quad = lane >> 4;

    if (t < 256) {
        int e = eb + t;
        sDst[t] = (e < EE) ? ei[EE + e] : 0;
    }
    #pragma unroll 4
    for (int rep = 0; rep < 16; rep++) {
        int idx = rep * 256 + t;
        int el = idx >> 4, d4 = idx & 15;
        int e = eb + el;
        float4 v = {0.f, 0.f, 0.f, 0.f};
        if (e < EE) {
            int src = ei[e];
            v = *(const float4*)(hv + (size_t)src * 64 + d4 * 4);
        }
        half4 h4 = {(_Float16)v.x, (_Float16)v.y, (_Float16)v.z, (_Float16)v.w};
        *(half4*)&sXs[el * 68 + d4 * 4] = h4;
    }

    half8 heReg[4][4];
    #pragma unroll
    for (int mt = 0; mt < 4; mt++) {
        int row = eb + w * 64 + mt * 16 + col;
        #pragma unroll
        for (int p = 0; p < 4; p++)
            heReg[mt][p] = *(const half8*)(he16 + (size_t)row * 128 + p * 32 + quad * 8);
    }

    floatx4 Cacc[4][4];
    #pragma unroll
    for (int mt = 0; mt < 4; mt++)
        #pragma unroll
        for (int nt = 0; nt < 4; nt++)
            Cacc[mt][nt] = (floatx4){0.f, 0.f, 0.f, 0.f};

    const size_t gbase = (size_t)(w * 16 + col) * 8192 + quad * 8;
    half8 pre[4];
    {
        #pragma unroll
        for (int rep = 0; rep < 4; rep++)
            pre[rep] = *(const half8*)(W2rT + gbase + 0 * 128 + rep * 32);
        #pragma unroll
        for (int rep = 0; rep < 4; rep++)
            *(half8*)&sB[0][((w * 4 + rep) * 64 + lane) * 8] = pre[rep];
    }
    __syncthreads();

    #pragma unroll 1
    for (int i = 0; i < 64; i++) {
        int buf = i & 1;
        if (i < 63) {
            #pragma unroll
            for (int rep = 0; rep < 4; rep++)
                pre[rep] = *(const half8*)(W2rT + gbase + (size_t)(i + 1) * 128 + rep * 32);
        }
        _Float16 xsx[4];
        #pragma unroll
        for (int mt = 0; mt < 4; mt++)
            xsx[mt] = sXs[(w * 64 + mt * 16 + col) * 68 + i];
        #pragma unroll
        for (int ks = 0; ks < 4; ks++) {
            half8 bfr[4];
            #pragma unroll
            for (int nt = 0; nt < 4; nt++)
                bfr[nt] = *(const half8*)&sB[buf][((nt * 4 + ks) * 64 + lane) * 8];
            #pragma unroll
            for (int mt = 0; mt < 4; mt++) {
                half8 afr = heReg[mt][ks] * xsx[mt];
                #pragma unroll
                for (int nt = 0; nt < 4; nt++)
                    Cacc[mt][nt] = __builtin_amdgcn_mfma_f32_16x16x32_f16(afr, bfr[nt], Cacc[mt][nt], 0, 0, 0);
            }
        }
        if (i < 63) {
            #pragma unroll
            for (int rep = 0; rep < 4; rep++)
                *(half8*)&sB[buf ^ 1][((w * 4 + rep) * 64 + lane) * 8] = pre[rep];
        }
        __syncthreads();
    }

    #pragma unroll
    for (int mt = 0; mt < 4; mt++) {
        #pragma unroll
        for (int r = 0; r < 4; r++) {
            int el = w * 64 + mt * 16 + quad * 4 + r;
            if (eb + el < EE) {
                float* ap = agg + (size_t)sDst[el] * 64 + col;
                #pragma unroll
                for (int nt = 0; nt < 4; nt++)
                    atomicAdd(ap + nt * 16, Cacc[mt][nt][r]);
            }
        }
    }
    #pragma unroll 4
    for (int rep = 0; rep < 64; rep++) {
        int idx = rep * 256 + t;
        int el = idx >> 6, d = idx & 63;
        if (eb + el < EE)
            atomicAdd(&xsum[(size_t)sDst[el] * 64 + d], (float)sXs[el * 68 + d]);
    }
}

// ---------------- msg GEMM v2: M=128/wave (tile 512), 1 block/CU, low LDS pressure ---
// Same frag layout/staging/barrier as v1; each B-frag read feeds 8 MFMAs (mt 0..7)
// -> per-CU LDS ~46% of the MFMA window instead of ~85%. heReg 128 + Cacc 128 VGPR
// fit the occupancy-1 budget (launch_bounds(256,1)); 32 indep acc chains give ILP.
__global__ __launch_bounds__(256, 1) void msg_gemm2_kernel(
    const float* __restrict__ hv, const _Float16* __restrict__ he16,
    const _Float16* __restrict__ W2rT, const int* __restrict__ ei,
    float* __restrict__ agg, float* __restrict__ xsum) {
    __shared__ _Float16 sB[2][16 * 64 * 8];   // 32KB
    __shared__ _Float16 sXs[512 * 68];        // 69.6KB
    __shared__ int sDst[512];
    const int t = threadIdx.x;
    const int eb = blockIdx.x * 512;
    const int lane = t & 63;
    const int w = t >> 6;
    const int col = lane & 15;
    const int quad = lane >> 4;

    #pragma unroll
    for (int rep = 0; rep < 2; rep++) {
        int idx = rep * 256 + t;
        int e = eb + idx;
        sDst[idx] = (e < EE) ? ei[EE + e] : 0;
    }
    #pragma unroll 4
    for (int rep = 0; rep < 32; rep++) {
        int idx = rep * 256 + t;
        int el = idx >> 4, d4 = idx & 15;
        int e = eb + el;
        float4 v = {0.f, 0.f, 0.f, 0.f};
        if (e < EE) {
            int src = ei[e];
            v = *(const float4*)(hv + (size_t)src * 64 + d4 * 4);
        }
        half4 h4 = {(_Float16)v.x, (_Float16)v.y, (_Float16)v.z, (_Float16)v.w};
        *(half4*)&sXs[el * 68 + d4 * 4] = h4;
    }

    half8 heReg[8][4];
    #pragma unroll
    for (int mt = 0; mt < 8; mt++) {
        int row = eb + w * 128 + mt * 16 + col;
        #pragma unroll
        for (int p = 0; p < 4; p++)
            heReg[mt][p] = *(const half8*)(he16 + (size_t)row * 128 + p * 32 + quad * 8);
    }

    floatx4 Cacc[8][4];
    #pragma unroll
    for (int mt = 0; mt < 8; mt++)
        #pragma unroll
        for (int nt = 0; nt < 4; nt++)
            Cacc[mt][nt] = (floatx4){0.f, 0.f, 0.f, 0.f};

    const size_t gbase = (size_t)(w * 16 + col) * 8192 + quad * 8;
    half8 pre[4];
    {
        #pragma unroll
        for (int rep = 0; rep < 4; rep++)
            pre[rep] = *(const half8*)(W2rT + gbase + 0 * 128 + rep * 32);
        #pragma unroll
        for (int rep = 0; rep < 4; rep++)
            *(half8*)&sB[0][((w * 4 + rep) * 64 + lane) * 8] = pre[rep];
    }
    __syncthreads();

    #pragma unroll 1
    for (int i = 0; i < 64; i++) {
        int buf = i & 1;
        if (i < 63) {
            #pragma unroll
            for (int rep = 0; rep < 4; rep++)
                pre[rep] = *(const half8*)(W2rT + gbase + (size_t)(i + 1) * 128 + rep * 32);
        }
        _Float16 xsx[8];
        #pragma unroll
        for (int mt = 0; mt < 8; mt++)
            xsx[mt] = sXs[(w * 128 + mt * 16 + col) * 68 + i];
        #pragma unroll
        for (int ks = 0; ks < 4; ks++) {
            half8 bfr[4];
            #pragma unroll
            for (int nt = 0; nt < 4; nt++)
                bfr[nt] = *(const half8*)&sB[buf][((nt * 4 + ks) * 64 + lane) * 8];
            #pragma unroll
            for (int mt = 0; mt < 8; mt++) {
                half8 afr = heReg[mt][ks] * xsx[mt];
                #pragma unroll
                for (int nt = 0; nt < 4; nt++)
                    Cacc[mt][nt] = __builtin_amdgcn_mfma_f32_16x16x32_f16(afr, bfr[nt], Cacc[mt][nt], 0, 0, 0);
            }
        }
        if (i < 63) {
            #pragma unroll
            for (int rep = 0; rep < 4; rep++)
                *(half8*)&sB[buf ^ 1][((w * 4 + rep) * 64 + lane) * 8] = pre[rep];
        }
        __syncthreads();
    }

    #pragma unroll
    for (int mt = 0; mt < 8; mt++) {
        #pragma unroll
        for (int r = 0; r < 4; r++) {
            int el = w * 128 + mt * 16 + quad * 4 + r;
            if (eb + el < EE) {
                float* ap = agg + (size_t)sDst[el] * 64 + col;
                #pragma unroll
                for (int nt = 0; nt < 4; nt++)
                    atomicAdd(ap + nt * 16, Cacc[mt][nt][r]);
            }
        }
    }
    #pragma unroll 4
    for (int rep = 0; rep < 128; rep++) {
        int idx = rep * 256 + t;
        int el = idx >> 6, d = idx & 63;
        if (eb + el < EE)
            atomicAdd(&xsum[(size_t)sDst[el] * 64 + d], (float)sXs[el * 68 + d]);
    }
}

// ---------------- fused node update: NNConv epilogue + GRU (MFMA) ----------------
__global__ __launch_bounds__(256, 2) void node_fused_kernel(
    const float* __restrict__ hv_in, float* __restrict__ agg,
    float* __restrict__ xsum, const float* __restrict__ deg,
    const _Float16* __restrict__ W1h, const _Float16* __restrict__ W2h,
    const float* __restrict__ fbias, const float* __restrict__ cb,
    float* __restrict__ hv_out) {
    __shared__ _Float16 sA1[64 * 136];
    __shared__ _Float16 sA2[64 * 136];
    __shared__ float sH[64 * 68];
    __shared__ float sAgg[64 * 68];
    const int t = threadIdx.x;
    const int nb = blockIdx.x * 64;
    const int n = t >> 2, part = t & 3;
    {
        int gn = nb + n;
        bool valid = gn < NN;
        float inv = 1.f;
        if (valid) inv = 1.f / fmaxf(deg[gn], 1.f);
        #pragma unroll
        for (int c4 = 0; c4 < 4; c4++) {
            int d0 = part * 16 + c4 * 4;
            float4 hvv = {0.f, 0.f, 0.f, 0.f}, agv = {0.f, 0.f, 0.f, 0.f}, xsv = {0.f, 0.f, 0.f, 0.f};
            if (valid) {
                hvv = *(const float4*)(hv_in + (size_t)gn * 64 + d0);
                agv = *(const float4*)(agg + (size_t)gn * 64 + d0);
                xsv = *(const float4*)(xsum + (size_t)gn * 64 + d0);
            }
            agv.x *= inv; agv.y *= inv; agv.z *= inv; agv.w *= inv;
            xsv.x *= inv; xsv.y *= inv; xsv.z *= inv; xsv.w *= inv;
            half4 hvh = {(_Float16)hvv.x, (_Float16)hvv.y, (_Float16)hvv.z, (_Float16)hvv.w};
            half4 xsh = {(_Float16)xsv.x, (_Float16)xsv.y, (_Float16)xsv.z, (_Float16)xsv.w};
            *(half4*)&sA1[n * 136 + d0] = hvh;
            *(half4*)&sA1[n * 136 + 64 + d0] = xsh;
            *(half4*)&sA2[n * 136 + 64 + d0] = hvh;
            *(float4*)&sH[n * 68 + d0] = hvv;
            *(float4*)&sAgg[n * 68 + d0] = agv;
        }
        if (valid) {
            float4 z = {0.f, 0.f, 0.f, 0.f};
            #pragma unroll
            for (int c4 = 0; c4 < 4; c4++) {
                int d0 = part * 16 + c4 * 4;
                *(float4*)(agg + (size_t)gn * 64 + d0) = z;
                *(float4*)(xsum + (size_t)gn * 64 + d0) = z;
            }
        }
    }
    __syncthreads();

    const int lane = t & 63, w = t >> 6;
    const int col = lane & 15, quad = lane >> 4;

    floatx4 C1[4];
    #pragma unroll
    for (int nt = 0; nt < 4; nt++) {
        float b = cb[nt * 16 + col];
        C1[nt] = (floatx4){b, b, b, b};
    }
    #pragma unroll
    for (int ks = 0; ks < 4; ks++) {
        half8 a = *(const half8*)&sA1[(w * 16 + col) * 136 + ks * 32 + quad * 8];
        #pragma unroll
        for (int nt = 0; nt < 4; nt++) {
            half8 bfr = *(const half8*)(W1h + (size_t)(nt * 16 + col) * 128 + ks * 32 + quad * 8);
            C1[nt] = __builtin_amdgcn_mfma_f32_16x16x32_f16(a, bfr, C1[nt], 0, 0, 0);
        }
    }
    #pragma unroll
    for (int nt = 0; nt < 4; nt++) {
        #pragma unroll
        for (int r = 0; r < 4; r++) {
            int node = w * 16 + quad * 4 + r;
            int j = nt * 16 + col;
            float m = fmaxf(C1[nt][r] + sAgg[node * 68 + j], 0.f);
            sA2[node * 136 + j] = (_Float16)m;
        }
    }
    __syncthreads();

    floatx4 C2[16];
    #pragma unroll
    for (int nt2 = 0; nt2 < 16; nt2++) {
        float b = fbias[nt2 * 16 + col];
        C2[nt2] = (floatx4){b, b, b, b};
    }
    #pragma unroll
    for (int ks = 0; ks < 4; ks++) {
        half8 a = *(const half8*)&sA2[(w * 16 + col) * 136 + ks * 32 + quad * 8];
        #pragma unroll
        for (int nt2 = 0; nt2 < 16; nt2++) {
            half8 bfr = *(const half8*)(W2h + (size_t)(nt2 * 16 + col) * 128 + ks * 32 + quad * 8);
            C2[nt2] = __builtin_amdgcn_mfma_f32_16x16x32_f16(a, bfr, C2[nt2], 0, 0, 0);
        }
    }
    float hnew[4][4];
    #pragma unroll
    for (int r = 0; r < 4; r++) {
        int node = w * 16 + quad * 4 + r;
        #pragma unroll
        for (int jt = 0; jt < 4; jt++) {
            int j = jt * 16 + col;
            float rr = sig_fast(C2[jt][r]);
            float zz = sig_fast(C2[4 + jt][r]);
            float ng = tanh_fast(C2[8 + jt][r] + rr * C2[12 + jt][r]);
            float hold = sH[node * 68 + j];
            hnew[r][jt] = (1.f - zz) * ng + zz * hold;
        }
    }
    __syncthreads();
    #pragma unroll
    for (int r = 0; r < 4; r++) {
        int node = w * 16 + quad * 4 + r;
        #pragma unroll
        for (int jt = 0; jt < 4; jt++)
            sH[node * 68 + jt * 16 + col] = hnew[r][jt];
    }
    __syncthreads();
    {
        int gn = nb + n;
        if (gn < NN) {
            #pragma unroll
            for (int c4 = 0; c4 < 4; c4++) {
                int d0 = part * 16 + c4 * 4;
                *(float4*)(hv_out + (size_t)gn * 64 + d0) = *(const float4*)&sH[n * 68 + d0];
            }
        }
    }
}

// ---------------- fused Set2Set (3 steps) + readout, one block per graph ----------------
__global__ __launch_bounds__(256) void set2set_kernel(
    const float* __restrict__ hv,
    const float* __restrict__ lihT, const float* __restrict__ lhhT,
    const float* __restrict__ l_bih, const float* __restrict__ l_bhh,
    const float* __restrict__ lin1T, const float* __restrict__ lin1_b,
    const float* __restrict__ lin2_w, const float* __restrict__ lin2_b,
    float* __restrict__ out) {
    __shared__ float outS[25 * 65];
    __shared__ float qs[128], qh[64], qc[64], gat[256], ew[32], aw[32], red[64];
    int g = blockIdx.x;
    int t = threadIdx.x;
    for (int p = t; p < 25 * 64; p += 256) {
        int j = p >> 6, i = p & 63;
        outS[j * 65 + i] = hv[(size_t)(g * 25 + j) * 64 + i];
    }
    if (t < 128) qs[t] = 0.f;
    if (t < 64) { qh[t] = 0.f; qc[t] = 0.f; }
    __syncthreads();
    for (int it = 0; it < 3; it++) {
        float acc = l_bih[t] + l_bhh[t];
        for (int k = 0; k < 128; k++) acc += qs[k] * lihT[k * 256 + t];
        for (int k = 0; k < 64; k++) acc += qh[k] * lhhT[k * 256 + t];
        gat[t] = acc;
        __syncthreads();
        if (t < 64) {
            float ig = sig_fast(gat[t]);
            float fg = sig_fast(gat[64 + t]);
            float gg = tanh_fast(gat[128 + t]);
            float og = sig_fast(gat[192 + t]);
            float c = fg * qc[t] + ig * gg;
            qc[t] = c;
            qh[t] = og * tanh_fast(c);
        }
        __syncthreads();
        if (t < 25) {
            float e = 0.f;
            for (int i = 0; i < 64; i++) e += outS[t * 65 + i] * qh[i];
            ew[t] = e;
        }
        __syncthreads();
        if (t == 0) {
            float mx = ew[0];
            for (int j = 1; j < 25; j++) mx = fmaxf(mx, ew[j]);
            float s = 0.f;
            for (int j = 0; j < 25; j++) { float a = __expf(ew[j] - mx); aw[j] = a; s += a; }
            float inv = rcp_fast(s);
            for (int j = 0; j < 25; j++) aw[j] *= inv;
        }
        __syncthreads();
        if (t < 64) {
            float r = 0.f;
            for (int j = 0; j < 25; j++) r += aw[j] * outS[j * 65 + t];
            qs[t] = qh[t];
            qs[64 + t] = r;
        }
        __syncthreads();
    }
    if (t < 64) {
        float y1 = lin1_b[t];
        for (int k = 0; k < 128; k++) y1 += qs[k] * lin1T[k * 64 + t];
        y1 = fmaxf(y1, 0.f);
        red[t] = y1 * lin2_w[t];
    }
    __syncthreads();
    if (t == 0) {
        float y = lin2_b[0];
        for (int i = 0; i < 64; i++) y += red[i];
        out[g] = y;
    }
}

extern "C" void kernel_launch(void* const* d_in, const int* in_sizes, int n_in,
                              void* d_out, int out_size, void* d_ws, size_t ws_size,
                              hipStream_t stream) {
    const float* x        = (const float*)d_in[0];
    const float* ea       = (const float*)d_in[1];
    const int*   ei       = (const int*)  d_in[2];
    const float* lin0_w   = (const float*)d_in[4];
    const float* lin0_b   = (const float*)d_in[5];
    const float* mlp_w1   = (const float*)d_in[6];
    const float* mlp_b1   = (const float*)d_in[7];
    const float* mlp_w2   = (const float*)d_in[8];
    const float* mlp_b2   = (const float*)d_in[9];
    const float* root     = (const float*)d_in[10];
    const float* conv_b   = (const float*)d_in[11];
    const float* gru_wih  = (const float*)d_in[12];
    const float* gru_whh  = (const float*)d_in[13];
    const float* gru_bih  = (const float*)d_in[14];
    const float* gru_bhh  = (const float*)d_in[15];
    const float* lstm_wih = (const float*)d_in[16];
    const float* lstm_whh = (const float*)d_in[17];
    const float* lstm_bih = (const float*)d_in[18];
    const float* lstm_bhh = (const float*)d_in[19];
    const float* lin1_w   = (const float*)d_in[20];
    const float* lin1_b   = (const float*)d_in[21];
    const float* lin2_w   = (const float*)d_in[22];
    const float* lin2_b   = (const float*)d_in[23];
    float* out = (float*)d_out;

    // ---- workspace carve ----
    char* base = (char*)d_ws;
    size_t off = 0;
    auto carve = [&](size_t bytes) -> void* {
        void* r = base + off;
        off = (off + bytes + 255) & ~(size_t)255;
        return r;
    };
    float* hv   = (float*)carve((size_t)NN * 64 * 4);
    float* agg  = (float*)carve((size_t)NN * 64 * 4);   // agg+xsum+deg adjacent: one memset
    float* xsum = (float*)carve((size_t)NN * 64 * 4);
    float* deg  = (float*)carve((size_t)NN * 4);
    float* lihT = (float*)carve(128 * 256 * 4);
    float* lhhT = (float*)carve(64 * 256 * 4);
    float* l1T  = (float*)carve(128 * 64 * 4);
    float* fbias = (float*)carve(256 * 4);
    _Float16* he16 = (_Float16*)carve((size_t)EPAD2 * 128 * 2);
    _Float16* W2rT = (_Float16*)carve((size_t)64 * 8192 * 2);
    _Float16* W1h  = (_Float16*)carve((size_t)64 * 128 * 2);
    _Float16* W2h  = (_Float16*)carve((size_t)256 * 128 * 2);

    // ---- preamble: one memset (agg+xsum+deg contiguous) + one fused prep kernel ----
    hipMemsetAsync(agg, 0, (size_t)NN * 64 * 4 * 2 + (size_t)NN * 4, stream);
    prep_fused_kernel<<<EPAD2 * 16 / 256, 256, 0, stream>>>(
        x, lin0_w, lin0_b, hv,
        ea, mlp_w1, mlp_b1, he16, ei, deg,
        mlp_w2, W2rT,
        lstm_wih, lstm_whh, lin1_w, lihT, lhhT, l1T,
        root, mlp_b2, gru_wih, gru_whh, gru_bih, gru_bhh,
        W1h, W2h, fbias);

    // ---- 3 message-passing + GRU iterations ----
    // it=0 runs the v2 (M=128/wave) experiment; it=1,2 run the verified v1.
    // Within-run A/B: compare the msg dispatch timings in the counter CSV.
    for (int it = 0; it < 3; it++) {
        if (it == 0)
            msg_gemm2_kernel<<<EPAD2 / 512, 256, 0, stream>>>(hv, he16, W2rT, ei, agg, xsum);
        else
            msg_gemm_kernel<<<EPAD / 256, 256, 0, stream>>>(hv, he16, W2rT, ei, agg, xsum);
        node_fused_kernel<<<(NN + 63) / 64, 256, 0, stream>>>(hv, agg, xsum, deg,
                                                              W1h, W2h, fbias, conv_b, hv);
    }

    // ---- Set2Set + readout ----
    set2set_kernel<<<BB, 256, 0, stream>>>(hv, lihT, lhhT, lstm_bih, lstm_bhh,
                                           l1T, lin1_b, lin2_w, lin2_b, out);
}

// Round 8
// 731.899 us; speedup vs baseline: 1.5878x; 1.0499x over previous
//
#include <hip/hip_runtime.h>
#include <hip/hip_bf16.h>

#define NN 50000
#define EE 100000
#define BB 2000
#define DIM 64
#define NF 14
#define EF 4
#define HID 128
#define EPAD 100096   // 391 * 256   (msg tile grid)
#define EPAD2 100352  // he16 padded allocation

typedef __attribute__((ext_vector_type(8))) _Float16 half8;   // 4 VGPRs
typedef __attribute__((ext_vector_type(4))) _Float16 half4;
typedef __attribute__((ext_vector_type(4))) float floatx4;    // MFMA C/D

__device__ __forceinline__ float rcp_fast(float x) { return __builtin_amdgcn_rcpf(x); }
__device__ __forceinline__ float sig_fast(float x) { return rcp_fast(1.f + __expf(-x)); }
__device__ __forceinline__ float tanh_fast(float x) {
    float e = __expf(2.f * x);
    return 1.f - 2.f * rcp_fast(e + 1.f);
}

// ---------------- fused preamble: w2rt + transposes + gru-prep + he16(+deg) + lin0 ----
__global__ void prep_fused_kernel(
    const float* __restrict__ x, const float* __restrict__ lin0_w,
    const float* __restrict__ lin0_b, float* __restrict__ hv,
    const float* __restrict__ ea, const float* __restrict__ w1,
    const float* __restrict__ b1, _Float16* __restrict__ he,
    const int* __restrict__ ei, float* __restrict__ deg,
    const float* __restrict__ w2, _Float16* __restrict__ W2rT,
    const float* __restrict__ lih, const float* __restrict__ lhh,
    const float* __restrict__ l1, float* __restrict__ lihT,
    float* __restrict__ lhhT, float* __restrict__ l1T,
    const float* __restrict__ root, const float* __restrict__ b2,
    const float* __restrict__ gwih, const float* __restrict__ gwhh,
    const float* __restrict__ gbih, const float* __restrict__ gbhh,
    _Float16* __restrict__ W1h, _Float16* __restrict__ W2h,
    float* __restrict__ fbias) {
    int t = blockIdx.x * 256 + threadIdx.x;

    // --- he16 (vectorized, 8 h/thread) + deg atomic; rows >= EE zero-padded ---
    {
        int el = t >> 4, hc = t & 15;
        if (el < EPAD2) {
            half8 o8 = {0, 0, 0, 0, 0, 0, 0, 0};
            if (el < EE) {
                const float4 a = *(const float4*)(ea + (size_t)el * 4);
                #pragma unroll
                for (int j = 0; j < 8; j++) {
                    int h = hc * 8 + j;
                    const float4 w = *(const float4*)(w1 + h * 4);
                    float acc = fmaxf(b1[h] + a.x * w.x + a.y * w.y + a.z * w.z + a.w * w.w, 0.f);
                    o8[j] = (_Float16)acc;
                }
                if (hc == 0) atomicAdd(&deg[ei[EE + el]], 1.0f);
            }
            *(half8*)(he + (size_t)el * 128 + hc * 8) = o8;
        }
    }
    // --- lin0 (vectorized, 8 d/thread): t < NN*8 ---
    if (t < NN * 8) {
        int n = t >> 3, dc = t & 7;
        float xv[NF];
        #pragma unroll
        for (int f = 0; f < NF; f++) xv[f] = x[(size_t)n * NF + f];
        float o[8];
        #pragma unroll
        for (int j = 0; j < 8; j++) {
            int d = dc * 8 + j;
            float acc = lin0_b[d];
            #pragma unroll
            for (int f = 0; f < NF; f++) acc += xv[f] * lin0_w[d * NF + f];
            o[j] = fmaxf(acc, 0.f);
        }
        *(float4*)(hv + (size_t)n * 64 + dc * 8)     = make_float4(o[0], o[1], o[2], o[3]);
        *(float4*)(hv + (size_t)n * 64 + dc * 8 + 4) = make_float4(o[4], o[5], o[6], o[7]);
    }
    // --- w2rt (vectorized, 8 k/thread): t < 64*1024 ---
    if (t < 64 * 1024) {
        int o = t >> 10, kc = t & 1023;
        int k0 = kc * 8, i = k0 >> 7, h0 = k0 & 127;
        const float* src = w2 + (size_t)(i * 64 + o) * 128 + h0;
        const float4 a = *(const float4*)src;
        const float4 b = *(const float4*)(src + 4);
        half8 r = {(_Float16)a.x, (_Float16)a.y, (_Float16)a.z, (_Float16)a.w,
                   (_Float16)b.x, (_Float16)b.y, (_Float16)b.z, (_Float16)b.w};
        *(half8*)(W2rT + (size_t)o * 8192 + k0) = r;
    }
    // --- set2set weight transposes ---
    if (t < 256 * 128) { int j = t / 128, k = t % 128; lihT[k * 256 + j] = lih[t]; }
    if (t < 256 * 64) { int j = t / 64, k = t % 64; lhhT[k * 256 + j] = lhh[t]; }
    if (t < 64 * 128) { int d = t / 128, k = t % 128; l1T[k * 64 + d] = l1[t]; }
    // --- gru weight prep ---
    if (t < 64 * 128) {
        int n = t >> 7, k = t & 127;
        W1h[t] = (_Float16)(k < 64 ? root[k * 64 + n] : b2[(size_t)(k - 64) * 64 + n]);
    }
    if (t < 256 * 128) {
        int n2 = t >> 7, k = t & 127;
        int g = n2 >> 6, j = n2 & 63;
        float v;
        if (g == 0)      v = (k < 64) ? gwih[j * 64 + k]         : gwhh[j * 64 + (k - 64)];
        else if (g == 1) v = (k < 64) ? gwih[(64 + j) * 64 + k]  : gwhh[(64 + j) * 64 + (k - 64)];
        else if (g == 2) v = (k < 64) ? gwih[(128 + j) * 64 + k] : 0.f;
        else             v = (k < 64) ? 0.f                      : gwhh[(128 + j) * 64 + (k - 64)];
        W2h[t] = (_Float16)v;
    }
    if (t < 256) {
        int g = t >> 6, j = t & 63;
        float v = (g == 0) ? gbih[j] + gbhh[j]
                : (g == 1) ? gbih[64 + j] + gbhh[64 + j]
                : (g == 2) ? gbih[128 + j] : gbhh[128 + j];
        fbias[t] = v;
    }
}

// ---------------- msg GEMM: the verified 134us kernel + T5 setprio graft -------------
// Structure byte-identical to the round-(-1) kernel (256-edge tile, frag-order sB,
// reg-staged dbuf, 1 barrier/slice). Added: s_setprio(1/0) around the per-slice
// compute cluster -- with 2 independent blocks/CU (separate barrier domains) this is
// the attn-like regime where the CU scheduler can favor the MFMA-entering wave
// (m191 +4-7%), not the lockstep-null regime (m190).
__global__ __launch_bounds__(256, 2) void msg_gemm_kernel(
    const float* __restrict__ hv, const _Float16* __restrict__ he16,
    const _Float16* __restrict__ W2rT, const int* __restrict__ ei,
    float* __restrict__ agg, float* __restrict__ xsum) {
    __shared__ _Float16 sB[2][16 * 64 * 8];   // [frag(nt*4+ks)][lane][8]
    __shared__ _Float16 sXs[256 * 68];        // [edge][i], padded stride 68
    __shared__ int sDst[256];
    const int t = threadIdx.x;
    const int eb = blockIdx.x * 256;
    const int lane = t & 63;
    const int w = t >> 6;
    const int col = lane & 15;
    const int quad = lane >> 4;

    if (t < 256) {
        int e = eb + t;
        sDst[t] = (e < EE) ? ei[EE + e] : 0;
    }
    #pragma unroll 4
    for (int rep = 0; rep < 16; rep++) {
        int idx = rep * 256 + t;
        int el = idx >> 4, d4 = idx & 15;
        int e = eb + el;
        float4 v = {0.f, 0.f, 0.f, 0.f};
        if (e < EE) {
            int src = ei[e];
            v = *(const float4*)(hv + (size_t)src * 64 + d4 * 4);
        }
        half4 h4 = {(_Float16)v.x, (_Float16)v.y, (_Float16)v.z, (_Float16)v.w};
        *(half4*)&sXs[el * 68 + d4 * 4] = h4;
    }

    half8 heReg[4][4];
    #pragma unroll
    for (int mt = 0; mt < 4; mt++) {
        int row = eb + w * 64 + mt * 16 + col;
        #pragma unroll
        for (int p = 0; p < 4; p++)
            heReg[mt][p] = *(const half8*)(he16 + (size_t)row * 128 + p * 32 + quad * 8);
    }

    floatx4 Cacc[4][4];
    #pragma unroll
    for (int mt = 0; mt < 4; mt++)
        #pragma unroll
        for (int nt = 0; nt < 4; nt++)
            Cacc[mt][nt] = (floatx4){0.f, 0.f, 0.f, 0.f};

    const size_t gbase = (size_t)(w * 16 + col) * 8192 + quad * 8;
    half8 pre[4];
    {
        #pragma unroll
        for (int rep = 0; rep < 4; rep++)
            pre[rep] = *(const half8*)(W2rT + gbase + 0 * 128 + rep * 32);
        #pragma unroll
        for (int rep = 0; rep < 4; rep++)
            *(half8*)&sB[0][((w * 4 + rep) * 64 + lane) * 8] = pre[rep];
    }
    __syncthreads();

    #pragma unroll 1
    for (int i = 0; i < 64; i++) {
        int buf = i & 1;
        if (i < 63) {
            #pragma unroll
            for (int rep = 0; rep < 4; rep++)
                pre[rep] = *(const half8*)(W2rT + gbase + (size_t)(i + 1) * 128 + rep * 32);
        }
        _Float16 xsx[4];
        #pragma unroll
        for (int mt = 0; mt < 4; mt++)
            xsx[mt] = sXs[(w * 64 + mt * 16 + col) * 68 + i];
        __builtin_amdgcn_s_setprio(1);
        #pragma unroll
        for (int ks = 0; ks < 4; ks++) {
            half8 bfr[4];
            #pragma unroll
            for (int nt = 0; nt < 4; nt++)
                bfr[nt] = *(const half8*)&sB[buf][((nt * 4 + ks) * 64 + lane) * 8];
            #pragma unroll
            for (int mt = 0; mt < 4; mt++) {
                half8 afr = heReg[mt][ks] * xsx[mt];
                #pragma unroll
                for (int nt = 0; nt < 4; nt++)
                    Cacc[mt][nt] = __builtin_amdgcn_mfma_f32_16x16x32_f16(afr, bfr[nt], Cacc[mt][nt], 0, 0, 0);
            }
        }
        __builtin_amdgcn_s_setprio(0);
        if (i < 63) {
            #pragma unroll
            for (int rep = 0; rep < 4; rep++)
                *(half8*)&sB[buf ^ 1][((w * 4 + rep) * 64 + lane) * 8] = pre[rep];
        }
        __syncthreads();
    }

    #pragma unroll
    for (int mt = 0; mt < 4; mt++) {
        #pragma unroll
        for (int r = 0; r < 4; r++) {
            int el = w * 64 + mt * 16 + quad * 4 + r;
            if (eb + el < EE) {
                float* ap = agg + (size_t)sDst[el] * 64 + col;
                #pragma unroll
                for (int nt = 0; nt < 4; nt++)
                    atomicAdd(ap + nt * 16, Cacc[mt][nt][r]);
            }
        }
    }
    #pragma unroll 4
    for (int rep = 0; rep < 64; rep++) {
        int idx = rep * 256 + t;
        int el = idx >> 6, d = idx & 63;
        if (eb + el < EE)
            atomicAdd(&xsum[(size_t)sDst[el] * 64 + d], (float)sXs[el * 68 + d]);
    }
}

// ---------------- fused node update: NNConv epilogue + GRU (MFMA) ----------------
// Round-13: sH LDS round-trip removed. Epilogue reads hold directly from hv_in
// (L2-hot, 64B-segment pattern, same per-lane addresses as the store -> no hazard;
// rows are block-exclusive) and stores hnew straight to hv_out. Removes 2 barriers
// + the whole sH store phase; LDS 69.6 -> 52.2 KB -> 3 blocks/CU.
__global__ __launch_bounds__(256, 3) void node_fused_kernel(
    const float* __restrict__ hv_in, float* __restrict__ agg,
    float* __restrict__ xsum, const float* __restrict__ deg,
    const _Float16* __restrict__ W1h, const _Float16* __restrict__ W2h,
    const float* __restrict__ fbias, const float* __restrict__ cb,
    float* __restrict__ hv_out) {
    __shared__ _Float16 sA1[64 * 136];  // [node][k]: k<64 hv, k>=64 xsum/deg
    __shared__ _Float16 sA2[64 * 136];  // [node][k]: k<64 m, k>=64 hv
    __shared__ float sAgg[64 * 68];     // agg/deg fp32
    const int t = threadIdx.x;
    const int nb = blockIdx.x * 64;
    const int n = t >> 2, part = t & 3;
    {
        int gn = nb + n;
        bool valid = gn < NN;
        float inv = 1.f;
        if (valid) inv = 1.f / fmaxf(deg[gn], 1.f);
        #pragma unroll
        for (int c4 = 0; c4 < 4; c4++) {
            int d0 = part * 16 + c4 * 4;
            float4 hvv = {0.f, 0.f, 0.f, 0.f}, agv = {0.f, 0.f, 0.f, 0.f}, xsv = {0.f, 0.f, 0.f, 0.f};
            if (valid) {
                hvv = *(const float4*)(hv_in + (size_t)gn * 64 + d0);
                agv = *(const float4*)(agg + (size_t)gn * 64 + d0);
                xsv = *(const float4*)(xsum + (size_t)gn * 64 + d0);
            }
            agv.x *= inv; agv.y *= inv; agv.z *= inv; agv.w *= inv;
            xsv.x *= inv; xsv.y *= inv; xsv.z *= inv; xsv.w *= inv;
            half4 hvh = {(_Float16)hvv.x, (_Float16)hvv.y, (_Float16)hvv.z, (_Float16)hvv.w};
            half4 xsh = {(_Float16)xsv.x, (_Float16)xsv.y, (_Float16)xsv.z, (_Float16)xsv.w};
            *(half4*)&sA1[n * 136 + d0] = hvh;
            *(half4*)&sA1[n * 136 + 64 + d0] = xsh;
            *(half4*)&sA2[n * 136 + 64 + d0] = hvh;
            *(float4*)&sAgg[n * 68 + d0] = agv;
        }
        // re-zero agg/xsum for the next msg_gemm launch
        if (valid) {
            float4 z = {0.f, 0.f, 0.f, 0.f};
            #pragma unroll
            for (int c4 = 0; c4 < 4; c4++) {
                int d0 = part * 16 + c4 * 4;
                *(float4*)(agg + (size_t)gn * 64 + d0) = z;
                *(float4*)(xsum + (size_t)gn * 64 + d0) = z;
            }
        }
    }
    __syncthreads();

    const int lane = t & 63, w = t >> 6;
    const int col = lane & 15, quad = lane >> 4;

    // ---- stage 1 ----
    floatx4 C1[4];
    #pragma unroll
    for (int nt = 0; nt < 4; nt++) {
        float b = cb[nt * 16 + col];
        C1[nt] = (floatx4){b, b, b, b};
    }
    #pragma unroll
    for (int ks = 0; ks < 4; ks++) {
        half8 a = *(const half8*)&sA1[(w * 16 + col) * 136 + ks * 32 + quad * 8];
        #pragma unroll
        for (int nt = 0; nt < 4; nt++) {
            half8 bfr = *(const half8*)(W1h + (size_t)(nt * 16 + col) * 128 + ks * 32 + quad * 8);
            C1[nt] = __builtin_amdgcn_mfma_f32_16x16x32_f16(a, bfr, C1[nt], 0, 0, 0);
        }
    }
    #pragma unroll
    for (int nt = 0; nt < 4; nt++) {
        #pragma unroll
        for (int r = 0; r < 4; r++) {
            int node = w * 16 + quad * 4 + r;
            int j = nt * 16 + col;
            float m = fmaxf(C1[nt][r] + sAgg[node * 68 + j], 0.f);
            sA2[node * 136 + j] = (_Float16)m;
        }
    }
    __syncthreads();

    // ---- stage 2 ----
    floatx4 C2[16];
    #pragma unroll
    for (int nt2 = 0; nt2 < 16; nt2++) {
        float b = fbias[nt2 * 16 + col];
        C2[nt2] = (floatx4){b, b, b, b};
    }
    #pragma unroll
    for (int ks = 0; ks < 4; ks++) {
        half8 a = *(const half8*)&sA2[(w * 16 + col) * 136 + ks * 32 + quad * 8];
        #pragma unroll
        for (int nt2 = 0; nt2 < 16; nt2++) {
            half8 bfr = *(const half8*)(W2h + (size_t)(nt2 * 16 + col) * 128 + ks * 32 + quad * 8);
            C2[nt2] = __builtin_amdgcn_mfma_f32_16x16x32_f16(a, bfr, C2[nt2], 0, 0, 0);
        }
    }
    // ---- GRU epilogue: direct global hold-read + store (no sH round-trip) ----
    #pragma unroll
    for (int r = 0; r < 4; r++) {
        int node = w * 16 + quad * 4 + r;
        int gn2 = nb + node;
        if (gn2 < NN) {
            #pragma unroll
            for (int jt = 0; jt < 4; jt++) {
                int j = jt * 16 + col;
                float rr = sig_fast(C2[jt][r]);
                float zz = sig_fast(C2[4 + jt][r]);
                float ng = tanh_fast(C2[8 + jt][r] + rr * C2[12 + jt][r]);
                float hold = hv_in[(size_t)gn2 * 64 + j];
                hv_out[(size_t)gn2 * 64 + j] = (1.f - zz) * ng + zz * hold;
            }
        }
    }
}

// ---------------- fused Set2Set (3 steps) + readout, one block per graph ----------------
__global__ __launch_bounds__(256) void set2set_kernel(
    const float* __restrict__ hv,
    const float* __restrict__ lihT, const float* __restrict__ lhhT,
    const float* __restrict__ l_bih, const float* __restrict__ l_bhh,
    const float* __restrict__ lin1T, const float* __restrict__ lin1_b,
    const float* __restrict__ lin2_w, const float* __restrict__ lin2_b,
    float* __restrict__ out) {
    __shared__ float outS[25 * 65];
    __shared__ float qs[128], qh[64], qc[64], gat[256], ew[32], aw[32], red[64];
    int g = blockIdx.x;
    int t = threadIdx.x;
    for (int p = t; p < 25 * 64; p += 256) {
        int j = p >> 6, i = p & 63;
        outS[j * 65 + i] = hv[(size_t)(g * 25 + j) * 64 + i];
    }
    if (t < 128) qs[t] = 0.f;
    if (t < 64) { qh[t] = 0.f; qc[t] = 0.f; }
    __syncthreads();
    for (int it = 0; it < 3; it++) {
        float acc = l_bih[t] + l_bhh[t];
        for (int k = 0; k < 128; k++) acc += qs[k] * lihT[k * 256 + t];
        for (int k = 0; k < 64; k++) acc += qh[k] * lhhT[k * 256 + t];
        gat[t] = acc;
        __syncthreads();
        if (t < 64) {
            float ig = sig_fast(gat[t]);
            float fg = sig_fast(gat[64 + t]);
            float gg = tanh_fast(gat[128 + t]);
            float og = sig_fast(gat[192 + t]);
            float c = fg * qc[t] + ig * gg;
            qc[t] = c;
            qh[t] = og * tanh_fast(c);
        }
        __syncthreads();
        if (t < 25) {
            float e = 0.f;
            for (int i = 0; i < 64; i++) e += outS[t * 65 + i] * qh[i];
            ew[t] = e;
        }
        __syncthreads();
        if (t == 0) {
            float mx = ew[0];
            for (int j = 1; j < 25; j++) mx = fmaxf(mx, ew[j]);
            float s = 0.f;
            for (int j = 0; j < 25; j++) { float a = __expf(ew[j] - mx); aw[j] = a; s += a; }
            float inv = rcp_fast(s);
            for (int j = 0; j < 25; j++) aw[j] *= inv;
        }
        __syncthreads();
        if (t < 64) {
            float r = 0.f;
            for (int j = 0; j < 25; j++) r += aw[j] * outS[j * 65 + t];
            qs[t] = qh[t];
            qs[64 + t] = r;
        }
        __syncthreads();
    }
    if (t < 64) {
        float y1 = lin1_b[t];
        for (int k = 0; k < 128; k++) y1 += qs[k] * lin1T[k * 64 + t];
        y1 = fmaxf(y1, 0.f);
        red[t] = y1 * lin2_w[t];
    }
    __syncthreads();
    if (t == 0) {
        float y = lin2_b[0];
        for (int i = 0; i < 64; i++) y += red[i];
        out[g] = y;
    }
}

extern "C" void kernel_launch(void* const* d_in, const int* in_sizes, int n_in,
                              void* d_out, int out_size, void* d_ws, size_t ws_size,
                              hipStream_t stream) {
    const float* x        = (const float*)d_in[0];
    const float* ea       = (const float*)d_in[1];
    const int*   ei       = (const int*)  d_in[2];
    const float* lin0_w   = (const float*)d_in[4];
    const float* lin0_b   = (const float*)d_in[5];
    const float* mlp_w1   = (const float*)d_in[6];
    const float* mlp_b1   = (const float*)d_in[7];
    const float* mlp_w2   = (const float*)d_in[8];
    const float* mlp_b2   = (const float*)d_in[9];
    const float* root     = (const float*)d_in[10];
    const float* conv_b   = (const float*)d_in[11];
    const float* gru_wih  = (const float*)d_in[12];
    const float* gru_whh  = (const float*)d_in[13];
    const float* gru_bih  = (const float*)d_in[14];
    const float* gru_bhh  = (const float*)d_in[15];
    const float* lstm_wih = (const float*)d_in[16];
    const float* lstm_whh = (const float*)d_in[17];
    const float* lstm_bih = (const float*)d_in[18];
    const float* lstm_bhh = (const float*)d_in[19];
    const float* lin1_w   = (const float*)d_in[20];
    const float* lin1_b   = (const float*)d_in[21];
    const float* lin2_w   = (const float*)d_in[22];
    const float* lin2_b   = (const float*)d_in[23];
    float* out = (float*)d_out;

    // ---- workspace carve ----
    char* base = (char*)d_ws;
    size_t off = 0;
    auto carve = [&](size_t bytes) -> void* {
        void* r = base + off;
        off = (off + bytes + 255) & ~(size_t)255;
        return r;
    };
    float* hv   = (float*)carve((size_t)NN * 64 * 4);
    float* agg  = (float*)carve((size_t)NN * 64 * 4);   // agg+xsum+deg adjacent: one memset
    float* xsum = (float*)carve((size_t)NN * 64 * 4);
    float* deg  = (float*)carve((size_t)NN * 4);
    float* lihT = (float*)carve(128 * 256 * 4);
    float* lhhT = (float*)carve(64 * 256 * 4);
    float* l1T  = (float*)carve(128 * 64 * 4);
    float* fbias = (float*)carve(256 * 4);
    _Float16* he16 = (_Float16*)carve((size_t)EPAD2 * 128 * 2);
    _Float16* W2rT = (_Float16*)carve((size_t)64 * 8192 * 2);
    _Float16* W1h  = (_Float16*)carve((size_t)64 * 128 * 2);
    _Float16* W2h  = (_Float16*)carve((size_t)256 * 128 * 2);

    // ---- preamble: one memset (agg+xsum+deg contiguous) + one fused prep kernel ----
    hipMemsetAsync(agg, 0, (size_t)NN * 64 * 4 * 2 + (size_t)NN * 4, stream);
    prep_fused_kernel<<<EPAD2 * 16 / 256, 256, 0, stream>>>(
        x, lin0_w, lin0_b, hv,
        ea, mlp_w1, mlp_b1, he16, ei, deg,
        mlp_w2, W2rT,
        lstm_wih, lstm_whh, lin1_w, lihT, lhhT, l1T,
        root, mlp_b2, gru_wih, gru_whh, gru_bih, gru_bhh,
        W1h, W2h, fbias);

    // ---- 3 message-passing + GRU iterations (node_fused re-zeros agg/xsum) ----
    for (int it = 0; it < 3; it++) {
        msg_gemm_kernel<<<EPAD / 256, 256, 0, stream>>>(hv, he16, W2rT, ei, agg, xsum);
        node_fused_kernel<<<(NN + 63) / 64, 256, 0, stream>>>(hv, agg, xsum, deg,
                                                              W1h, W2h, fbias, conv_b, hv);
    }

    // ---- Set2Set + readout ----
    set2set_kernel<<<BB, 256, 0, stream>>>(hv, lihT, lhhT, lstm_bih, lstm_bhh,
                                           l1T, lin1_b, lin2_w, lin2_b, out);
}